// Round 5
// baseline (440.700 us; speedup 1.0000x reference)
//
#include <hip/hip_runtime.h>
#include <math.h>

// ---------------------------------------------------------------------------
// DETR deformable-transformer encoder layer, MI355X — bf16 MFMA version.
// D=512, H=8, DFF=2048, K=4, S=4, DH=64, B=4
// token counts per scale (incl. batch): 12544, 3136, 784, 196 ; T=16660
// ---------------------------------------------------------------------------

#define TTOT 16660
#define TPAD 16768   // 131 * 128 = 262 * 64
#define LQTOT 4165

typedef __attribute__((ext_vector_type(8))) short bf16x8;
typedef __attribute__((ext_vector_type(4))) float f32x4;

typedef __attribute__((address_space(1))) const unsigned int g_u32;
typedef __attribute__((address_space(3))) unsigned int l_u32;

__device__ __forceinline__ unsigned short f2bf(float f) {
    unsigned u = __builtin_bit_cast(unsigned, f);
    u += 0x7fffu + ((u >> 16) & 1u);
    return (unsigned short)(u >> 16);
}
__device__ __forceinline__ float bf2f(unsigned short s) {
    unsigned u = ((unsigned)s) << 16;
    return __builtin_bit_cast(float, u);
}
__device__ __forceinline__ float bflo(unsigned u) {           // low bf16 of dword
    return __builtin_bit_cast(float, u << 16);
}
__device__ __forceinline__ float bfhi(unsigned u) {           // high bf16 of dword
    return __builtin_bit_cast(float, u & 0xffff0000u);
}

// token row -> row in d_out ([B, 4165, 512], scales concatenated per batch)
__device__ __forceinline__ int permute_row(int t) {
    int off, area, qoff;
    if (t < 12544)      { off = 0;     area = 3136; qoff = 0;    }
    else if (t < 15680) { off = 12544; area = 784;  qoff = 3136; }
    else if (t < 16464) { off = 15680; area = 196;  qoff = 3920; }
    else                { off = 16464; area = 49;   qoff = 4116; }
    int rel = t - off;
    int b = rel / area;
    int pos = rel - b * area;
    return b * LQTOT + qoff + pos;
}

// token row -> fp32 row pointer inside the 4 concatenated src arrays
__device__ __forceinline__ const float* src_row(int row, const float* s0, const float* s1,
                                                const float* s2, const float* s3) {
    if (row < 12544) return s0 + (size_t)row * 512;
    if (row < 15680) return s1 + (size_t)(row - 12544) * 512;
    if (row < 16464) return s2 + (size_t)(row - 15680) * 512;
    return s3 + (size_t)(row - 16464) * 512;
}

__device__ __forceinline__ void async_copy16(const unsigned short* g, unsigned short* lds_wave_uniform) {
    __builtin_amdgcn_global_load_lds((g_u32*)g, (l_u32*)lds_wave_uniform, 16, 0, 0);
}

// ---------------------------------------------------------------------------
// bf16 MFMA GEMM: C = A[M,Kd] @ (Bt[N,Kd])^T (+bias)(+epilogue)
// TM x 128 tile (TM=128 or 64), BK=32, 256 threads = 4 waves (2x2),
// 16x16x32 MFMA. TM=64 doubles grid parallelism for small-N GEMMs
// (N=512 at TM=128 gave only ~2 blocks/CU -> Occupancy 17%).
// ---------------------------------------------------------------------------
enum { EPI_SPLIT = 0, EPI_RESID_SRC = 1, EPI_RELU = 2, EPI_RESID_SCATTER = 3 };

struct GemmArgs {
    const unsigned short* A;    // [Mpad, Kd] bf16
    const unsigned short* Bt;   // [N, Kd]   bf16 (W^T)
    const float* bias0; const float* bias1; const float* bias2;
    const unsigned short* residb;   // bf16 residual (scatter epi)
    const float* s0; const float* s1; const float* s2; const float* s3; // fp32 resid gather
    void* out0; unsigned short* out1; unsigned short* out2;
    int M, N, Kd;
};

template <int EPI, int TM>
__global__ __launch_bounds__(256) void gemm_mfma(GemmArgs a)
{
    constexpr int MT = TM / 32;            // frag-rows per wave (4 or 2)
    __shared__ unsigned short As[TM * 32];
    __shared__ unsigned short Bs[128 * 32];
    const int tid  = threadIdx.x;
    const int wave = tid >> 6;
    const int lane = tid & 63;
    const int m0 = blockIdx.y * TM;
    const int n0 = blockIdx.x * 128;

    const int srow = tid >> 2;
    const int kg   = (tid & 3) ^ ((tid >> 3) & 3);
    const unsigned short* Ag = a.A  + (size_t)(m0 + srow) * a.Kd + kg * 8;
    const unsigned short* Bg = a.Bt + (size_t)(n0 + srow) * a.Kd + kg * 8;
    const size_t rstep = (size_t)64 * a.Kd;
    unsigned short* ldsA0 = As + wave * 512;
    unsigned short* ldsA1 = As + 2048 + wave * 512;   // TM=128 only
    unsigned short* ldsB0 = Bs + wave * 512;
    unsigned short* ldsB1 = Bs + 2048 + wave * 512;

    const int wm = (wave >> 1) * (MT * 16);
    const int wn = (wave & 1) << 6;
    const int fm = lane & 15;
    const int fq = lane >> 4;
    const int slot = (fq ^ ((fm >> 1) & 3)) << 3;

    const f32x4 fzero = {0.f, 0.f, 0.f, 0.f};
    f32x4 acc[MT][4];
#pragma unroll
    for (int i = 0; i < MT; ++i)
#pragma unroll
        for (int j = 0; j < 4; ++j) acc[i][j] = fzero;

    for (int k0 = 0; k0 < a.Kd; k0 += 32) {
        __syncthreads();
        async_copy16(Ag + k0, ldsA0);
        if (TM == 128) async_copy16(Ag + rstep + k0, ldsA1);
        async_copy16(Bg + k0,         ldsB0);
        async_copy16(Bg + rstep + k0, ldsB1);
        __syncthreads();
        bf16x8 af[MT], bfr[4];
#pragma unroll
        for (int mt = 0; mt < MT; ++mt)
            af[mt] = *(const bf16x8*)&As[(wm + mt * 16 + fm) * 32 + slot];
#pragma unroll
        for (int nt = 0; nt < 4; ++nt)
            bfr[nt] = *(const bf16x8*)&Bs[(wn + nt * 16 + fm) * 32 + slot];
#pragma unroll
        for (int mt = 0; mt < MT; ++mt)
#pragma unroll
            for (int nt = 0; nt < 4; ++nt)
                acc[mt][nt] = __builtin_amdgcn_mfma_f32_16x16x32_bf16(
                    af[mt], bfr[nt], acc[mt][nt], 0, 0, 0);
    }

    // epilogue — C/D layout: col = lane&15, row = (lane>>4)*4 + reg
    const int cn0 = n0 + wn + fm;
    int cols[4]; float bi[4];
#pragma unroll
    for (int nt = 0; nt < 4; ++nt) {
        const int c = cn0 + nt * 16;
        cols[nt] = c;
        if (EPI == EPI_SPLIT)
            bi[nt] = (c < 512) ? a.bias0[c] : (c < 768) ? a.bias1[c - 512] : a.bias2[c - 768];
        else
            bi[nt] = a.bias0[c];
    }
#pragma unroll
    for (int mt = 0; mt < MT; ++mt) {
#pragma unroll
        for (int r = 0; r < 4; ++r) {
            const int row = m0 + wm + mt * 16 + fq * 4 + r;
            if (row >= a.M) continue;
            const size_t ro = (size_t)row;
            const float* srcres = (EPI == EPI_RESID_SRC)
                                  ? src_row(row, a.s0, a.s1, a.s2, a.s3) : nullptr;
#pragma unroll
            for (int nt = 0; nt < 4; ++nt) {
                float v = acc[mt][nt][r] + bi[nt];
                const int c = cols[nt];
                if (EPI == EPI_SPLIT) {
                    if (c < 512)      ((unsigned short*)a.out0)[ro * 512 + c]        = f2bf(v);
                    else if (c < 768) a.out1[ro * 256 + (c - 512)]                   = f2bf(v);
                    else              a.out2[ro * 128 + (c - 768)]                   = f2bf(v);
                } else if (EPI == EPI_RESID_SRC) {
                    v += srcres[c];
                    ((unsigned short*)a.out0)[ro * 512 + c] = f2bf(v);
                } else if (EPI == EPI_RELU) {
                    v = fmaxf(v, 0.f);
                    ((unsigned short*)a.out0)[ro * 2048 + c] = f2bf(v);
                } else { // EPI_RESID_SCATTER
                    v += bf2f(a.residb[ro * 512 + c]);
                    ((float*)a.out0)[(size_t)permute_row(row) * 512 + c] = v;
                }
            }
        }
    }
}

// ---------------------------------------------------------------------------
// prep: all 6 weight transposes (fp32 [K,N] -> bf16 [N,K]) + Q concat in one
// launch. Blocks [0,2752) = 32x32 transpose tiles; [2752,11082) = concat.
// ---------------------------------------------------------------------------
struct PrepArgs {
    const float *Wv, *Woff, *Wattn, *Wo, *W1, *W2;
    unsigned short *Wcat, *Wot, *W1t, *W2t;
    const float *s0, *s1, *s2, *s3;
    unsigned short* Qb;
};

__global__ __launch_bounds__(256) void prep(PrepArgs p)
{
    __shared__ unsigned short t[32][33];
    const int bid = blockIdx.x;
    if (bid < 2752) {
        const float* W; unsigned short* Wt; int K, N, lbx, rel;
        if (bid < 256)       { W = p.Wv;    Wt = p.Wcat;                   K = 512;  N = 512;  lbx = 4; rel = bid; }
        else if (bid < 384)  { W = p.Woff;  Wt = p.Wcat + (size_t)512*512; K = 512;  N = 256;  lbx = 3; rel = bid - 256; }
        else if (bid < 448)  { W = p.Wattn; Wt = p.Wcat + (size_t)768*512; K = 512;  N = 128;  lbx = 2; rel = bid - 384; }
        else if (bid < 704)  { W = p.Wo;    Wt = p.Wot;                    K = 512;  N = 512;  lbx = 4; rel = bid - 448; }
        else if (bid < 1728) { W = p.W1;    Wt = p.W1t;                    K = 512;  N = 2048; lbx = 6; rel = bid - 704; }
        else                 { W = p.W2;    Wt = p.W2t;                    K = 2048; N = 512;  lbx = 4; rel = bid - 1728; }
        const int bx = rel & ((1 << lbx) - 1);
        const int by = rel >> lbx;
        const int tx = threadIdx.x & 31, ty = threadIdx.x >> 5;
        const int nb = bx * 32, kb = by * 32;
#pragma unroll
        for (int j = 0; j < 32; j += 8)
            t[ty + j][tx] = f2bf(W[(size_t)(kb + ty + j) * N + nb + tx]);
        __syncthreads();
#pragma unroll
        for (int j = 0; j < 32; j += 8)
            Wt[(size_t)(nb + ty + j) * K + kb + tx] = t[tx][ty + j];
    } else {
        const int gid = (bid - 2752) * 256 + threadIdx.x;   // over TTOT*128 exactly
        const int e = gid * 4;
        const int row = e >> 9, col = e & 511;
        const float* sr = src_row(row, p.s0, p.s1, p.s2, p.s3);
        const float4 v = *(const float4*)(sr + col);
        ushort4 o;
        o.x = f2bf(v.x); o.y = f2bf(v.y); o.z = f2bf(v.z); o.w = f2bf(v.w);
        *(ushort4*)(p.Qb + (size_t)row * 512 + col) = o;
    }
}

// ---------------------------------------------------------------------------
// deformable sampling v4: block = 2 tokens, 4 waves.
// Phase 1: all 256 threads, thread = (token_local, head, sample); softmax via
//   width-16 shuffles with denom folded into weights; clamped byte indices +
//   validity-zeroed weights -> LDS.
// Phase 2: wave = (token_local, head-quad); lane owns 4 packed bf16 channels
//   (dwordx2 gathers, 8 B/lane), 16 samples x 4 unconditional corners.
// ---------------------------------------------------------------------------
__global__ __launch_bounds__(256) void sample_attn(
    const unsigned short* __restrict__ Vp, const unsigned short* __restrict__ OFFB,
    const unsigned short* __restrict__ ATT,
    const float* __restrict__ rf0, const float* __restrict__ rf1,
    const float* __restrict__ rf2, const float* __restrict__ rf3,
    unsigned short* __restrict__ ACCb)
{
    __shared__ int   midx[2][8][16][4];
    __shared__ float mw[2][8][16][4];
    const int tid = threadIdx.x;

    // ---- phase 1: thread = (tl, h, s) ----
    {
        const int tl = tid >> 7;
        const int h  = (tid >> 4) & 7;
        const int s  = tid & 15;
        const int t  = blockIdx.x * 2 + tl;
        const int li = s >> 2;

        int soff, area;
        const float* rp;
        if (t < 12544)      { soff = 0;     area = 3136; rp = rf0 + (size_t)t * 2; }
        else if (t < 15680) { soff = 12544; area = 784;  rp = rf1 + (size_t)(t - 12544) * 2; }
        else if (t < 16464) { soff = 15680; area = 196;  rp = rf2 + (size_t)(t - 15680) * 2; }
        else                { soff = 16464; area = 49;   rp = rf3 + (size_t)(t - 16464) * 2; }
        const int b = (t - soff) / area;

        // softmax over 16 logits of this head (width-16 shuffle groups)
        float logit = bf2f(ATT[(size_t)t * 128 + h * 16 + s]);
        float mx = logit;
#pragma unroll
        for (int o = 8; o > 0; o >>= 1) mx = fmaxf(mx, __shfl_xor(mx, o, 16));
        float e = __expf(logit - mx);
        float sumv = e;
#pragma unroll
        for (int o = 8; o > 0; o >>= 1) sumv += __shfl_xor(sumv, o, 16);
        const float ew = e / sumv;         // softmax denom folded in

        // coords: (rx + ox/wl)*wl - 0.5 == rx*wl + ox - 0.5
        const int wl = 56 >> li;
        const int lvlbase = (li == 0) ? 0 : (li == 1) ? 12544 : (li == 2) ? 15680 : 16464;
        const int base = lvlbase + b * wl * wl;
        const float rx = rp[0], ry = rp[1];
        const unsigned off2 = *(const unsigned*)(OFFB + (size_t)t * 256 + h * 32 + s * 2);
        const float ox = bflo(off2);
        const float oy = bfhi(off2);
        const float x = rx * (float)wl + ox - 0.5f;
        const float y = ry * (float)wl + oy - 0.5f;
        const float x0f = floorf(x), y0f = floorf(y);
        const float wx1 = x - x0f, wx0 = 1.f - wx1;
        const float wy1 = y - y0f, wy0 = 1.f - wy1;
        const int x0 = (int)x0f, y0 = (int)y0f;
        const int x1 = x0 + 1, y1 = y0 + 1;
        const int xc0 = min(max(x0, 0), wl - 1), xc1 = min(max(x1, 0), wl - 1);
        const int yc0 = min(max(y0, 0), wl - 1), yc1 = min(max(y1, 0), wl - 1);
        const float fx0 = (x0 >= 0 && x0 < wl) ? 1.f : 0.f;
        const float fx1 = (x1 >= 0 && x1 < wl) ? 1.f : 0.f;
        const float fy0 = (y0 >= 0 && y0 < wl) ? 1.f : 0.f;
        const float fy1 = (y1 >= 0 && y1 < wl) ? 1.f : 0.f;
        const int hb2 = h * 128;           // head base, BYTES (64 ch * 2B)
        midx[tl][h][s][0] = (base + yc0 * wl + xc0) * 1024 + hb2;   // *512 elem *2B
        midx[tl][h][s][1] = (base + yc0 * wl + xc1) * 1024 + hb2;
        midx[tl][h][s][2] = (base + yc1 * wl + xc0) * 1024 + hb2;
        midx[tl][h][s][3] = (base + yc1 * wl + xc1) * 1024 + hb2;
        mw[tl][h][s][0] = wx0 * wy0 * fx0 * fy0 * ew;
        mw[tl][h][s][1] = wx1 * wy0 * fx1 * fy0 * ew;
        mw[tl][h][s][2] = wx0 * wy1 * fx0 * fy1 * ew;
        mw[tl][h][s][3] = wx1 * wy1 * fx1 * fy1 * ew;
    }
    __syncthreads();

    // ---- phase 2: wave = (tl, head-quad), lane owns 4 channels ----
    const int wave = tid >> 6;
    const int lane = tid & 63;
    const int tl = wave >> 1;
    const int h  = (wave & 1) * 4 + (lane >> 4);
    const int t  = blockIdx.x * 2 + tl;
    const int off8 = (lane & 15) * 8;      // byte offset within head's 128B row
    const char* vb = (const char*)Vp;
    float a0 = 0.f, a1 = 0.f, a2 = 0.f, a3 = 0.f;
#pragma unroll
    for (int s = 0; s < 16; ++s) {
        const int4   I = *(const int4*)&midx[tl][h][s][0];
        const float4 W = *(const float4*)&mw[tl][h][s][0];
        const uint2 u0 = *(const uint2*)(vb + (I.x + off8));
        const uint2 u1 = *(const uint2*)(vb + (I.y + off8));
        const uint2 u2 = *(const uint2*)(vb + (I.z + off8));
        const uint2 u3 = *(const uint2*)(vb + (I.w + off8));
        a0 += W.x * bflo(u0.x); a1 += W.x * bfhi(u0.x); a2 += W.x * bflo(u0.y); a3 += W.x * bfhi(u0.y);
        a0 += W.y * bflo(u1.x); a1 += W.y * bfhi(u1.x); a2 += W.y * bflo(u1.y); a3 += W.y * bfhi(u1.y);
        a0 += W.z * bflo(u2.x); a1 += W.z * bfhi(u2.x); a2 += W.z * bflo(u2.y); a3 += W.z * bfhi(u2.y);
        a0 += W.w * bflo(u3.x); a1 += W.w * bfhi(u3.x); a2 += W.w * bflo(u3.y); a3 += W.w * bfhi(u3.y);
    }
    ushort4 o;
    o.x = f2bf(a0); o.y = f2bf(a1); o.z = f2bf(a2); o.w = f2bf(a3);
    *(ushort4*)((char*)ACCb + (size_t)t * 1024 + h * 128 + off8) = o;
}

// in-place layernorm on bf16 rows of 512 (fp32 stats)
__global__ __launch_bounds__(256) void ln_bf16(
    unsigned short* __restrict__ X, const float* __restrict__ g, const float* __restrict__ be)
{
    const int row = blockIdx.x;
    unsigned short* xr = X + (size_t)row * 512;
    const int tid = threadIdx.x;
    float v0 = bf2f(xr[tid]);
    float v1 = bf2f(xr[tid + 256]);
    float s = v0 + v1;
    float ss = v0 * v0 + v1 * v1;
#pragma unroll
    for (int o = 32; o > 0; o >>= 1) {
        s += __shfl_down(s, o, 64);
        ss += __shfl_down(ss, o, 64);
    }
    __shared__ float sm[4], sm2[4];
    const int w = tid >> 6;
    if ((tid & 63) == 0) { sm[w] = s; sm2[w] = ss; }
    __syncthreads();
    if (tid == 0) {
        sm[0] = sm[0] + sm[1] + sm[2] + sm[3];
        sm2[0] = sm2[0] + sm2[1] + sm2[2] + sm2[3];
    }
    __syncthreads();
    const float mu = sm[0] * (1.f / 512.f);
    const float var = sm2[0] * (1.f / 512.f) - mu * mu;
    const float rs = rsqrtf(var + 1e-5f);
    xr[tid]       = f2bf((v0 - mu) * rs * g[tid]       + be[tid]);
    xr[tid + 256] = f2bf((v1 - mu) * rs * g[tid + 256] + be[tid + 256]);
}

// in-place fp32 layernorm (final, on d_out)
__global__ __launch_bounds__(256) void ln_f32(
    float* __restrict__ X, const float* __restrict__ g, const float* __restrict__ be)
{
    const int row = blockIdx.x;
    float* xr = X + (size_t)row * 512;
    const int tid = threadIdx.x;
    float v0 = xr[tid];
    float v1 = xr[tid + 256];
    float s = v0 + v1;
    float ss = v0 * v0 + v1 * v1;
#pragma unroll
    for (int o = 32; o > 0; o >>= 1) {
        s += __shfl_down(s, o, 64);
        ss += __shfl_down(ss, o, 64);
    }
    __shared__ float sm[4], sm2[4];
    const int w = tid >> 6;
    if ((tid & 63) == 0) { sm[w] = s; sm2[w] = ss; }
    __syncthreads();
    if (tid == 0) {
        sm[0] = sm[0] + sm[1] + sm[2] + sm[3];
        sm2[0] = sm2[0] + sm2[1] + sm2[2] + sm2[3];
    }
    __syncthreads();
    const float mu = sm[0] * (1.f / 512.f);
    const float var = sm2[0] * (1.f / 512.f) - mu * mu;
    const float rs = rsqrtf(var + 1e-5f);
    xr[tid]       = (v0 - mu) * rs * g[tid]       + be[tid];
    xr[tid + 256] = (v1 - mu) * rs * g[tid + 256] + be[tid + 256];
}

extern "C" void kernel_launch(void* const* d_in, const int* in_sizes, int n_in,
                              void* d_out, int out_size, void* d_ws, size_t ws_size,
                              hipStream_t stream)
{
    const float* src[4] = { (const float*)d_in[0], (const float*)d_in[2],
                            (const float*)d_in[4], (const float*)d_in[6] };
    const float* ref[4] = { (const float*)d_in[1], (const float*)d_in[3],
                            (const float*)d_in[5], (const float*)d_in[7] };
    const float* Wv    = (const float*)d_in[8];
    const float* bv    = (const float*)d_in[9];
    const float* Woff  = (const float*)d_in[10];
    const float* boff  = (const float*)d_in[11];
    const float* Wattn = (const float*)d_in[12];
    const float* battn = (const float*)d_in[13];
    const float* Wo    = (const float*)d_in[14];
    const float* bo    = (const float*)d_in[15];
    const float* W1    = (const float*)d_in[16];
    const float* b1    = (const float*)d_in[17];
    const float* W2    = (const float*)d_in[18];
    const float* b2    = (const float*)d_in[19];
    const float* g1    = (const float*)d_in[20];
    const float* be1   = (const float*)d_in[21];
    const float* g2    = (const float*)d_in[22];
    const float* be2   = (const float*)d_in[23];

    // workspace layout (bf16 == unsigned short)
    unsigned short* w    = (unsigned short*)d_ws;
    unsigned short* Qb   = w;                              // [TPAD,512]
    unsigned short* Vp   = Qb   + (size_t)TPAD * 512;      // [TPAD,512]
    unsigned short* OFFB = Vp   + (size_t)TPAD * 512;      // [TPAD,256]
    unsigned short* ATT  = OFFB + (size_t)TPAD * 256;      // [TPAD,128]
    unsigned short* ACCb = ATT  + (size_t)TPAD * 128;      // [TPAD,512]
    unsigned short* X1b  = ACCb + (size_t)TPAD * 512;      // [TPAD,512]
    unsigned short* Fb   = X1b  + (size_t)TPAD * 512;      // [TPAD,2048]
    unsigned short* Wcat = Fb   + (size_t)TPAD * 2048;     // [896,512]
    unsigned short* Wot  = Wcat + (size_t)896 * 512;       // [512,512]
    unsigned short* W1t  = Wot  + (size_t)512 * 512;       // [2048,512]
    unsigned short* W2t  = W1t  + (size_t)2048 * 512;      // [512,2048]

    const dim3 blk(256);

    PrepArgs pp = {};
    pp.Wv = Wv; pp.Woff = Woff; pp.Wattn = Wattn; pp.Wo = Wo; pp.W1 = W1; pp.W2 = W2;
    pp.Wcat = Wcat; pp.Wot = Wot; pp.W1t = W1t; pp.W2t = W2t;
    pp.s0 = src[0]; pp.s1 = src[1]; pp.s2 = src[2]; pp.s3 = src[3];
    pp.Qb = Qb;
    prep<<<dim3(11082), blk, 0, stream>>>(pp);

    // fused V/off/attn projection: [T,512] @ [512,896]
    GemmArgs a1 = {};
    a1.A = Qb; a1.Bt = Wcat; a1.bias0 = bv; a1.bias1 = boff; a1.bias2 = battn;
    a1.out0 = Vp; a1.out1 = OFFB; a1.out2 = ATT; a1.M = TTOT; a1.N = 896; a1.Kd = 512;
    gemm_mfma<EPI_SPLIT, 128><<<dim3(7, 131), blk, 0, stream>>>(a1);

    sample_attn<<<dim3(TTOT / 2), blk, 0, stream>>>(Vp, OFFB, ATT,
                                                    ref[0], ref[1], ref[2], ref[3], ACCb);

    // output projection + residual(q from srcs) — TM=64: 1048 blocks
    GemmArgs a2 = {};
    a2.A = ACCb; a2.Bt = Wot; a2.bias0 = bo;
    a2.s0 = src[0]; a2.s1 = src[1]; a2.s2 = src[2]; a2.s3 = src[3];
    a2.out0 = X1b; a2.M = TTOT; a2.N = 512; a2.Kd = 512;
    gemm_mfma<EPI_RESID_SRC, 64><<<dim3(4, 262), blk, 0, stream>>>(a2);

    ln_bf16<<<dim3(TTOT), blk, 0, stream>>>(X1b, g1, be1);

    // FFN up + relu
    GemmArgs a3 = {};
    a3.A = X1b; a3.Bt = W1t; a3.bias0 = b1;
    a3.out0 = Fb; a3.M = TTOT; a3.N = 2048; a3.Kd = 512;
    gemm_mfma<EPI_RELU, 128><<<dim3(16, 131), blk, 0, stream>>>(a3);

    // FFN down + residual(x) + scatter into d_out layout — TM=64: 1048 blocks
    GemmArgs a4 = {};
    a4.A = Fb; a4.Bt = W2t; a4.bias0 = b2; a4.residb = X1b;
    a4.out0 = d_out; a4.M = TTOT; a4.N = 512; a4.Kd = 2048;
    gemm_mfma<EPI_RESID_SCATTER, 64><<<dim3(4, 262), blk, 0, stream>>>(a4);

    ln_f32<<<dim3(TTOT), blk, 0, stream>>>((float*)d_out, g2, be2);
}

// Round 6
// 400.942 us; speedup vs baseline: 1.0992x; 1.0992x over previous
//
#include <hip/hip_runtime.h>
#include <math.h>

// ---------------------------------------------------------------------------
// DETR deformable-transformer encoder layer, MI355X — bf16 MFMA version.
// D=512, H=8, DFF=2048, K=4, S=4, DH=64, B=4
// token counts per scale (incl. batch): 12544, 3136, 784, 196 ; T=16660
// ---------------------------------------------------------------------------

#define TTOT 16660
#define TPAD 16768   // 131 * 128
#define LQTOT 4165

typedef __attribute__((ext_vector_type(8))) short bf16x8;
typedef __attribute__((ext_vector_type(4))) float f32x4;

typedef __attribute__((address_space(1))) const unsigned int g_u32;
typedef __attribute__((address_space(3))) unsigned int l_u32;

__device__ __forceinline__ unsigned short f2bf(float f) {
    unsigned u = __builtin_bit_cast(unsigned, f);
    u += 0x7fffu + ((u >> 16) & 1u);
    return (unsigned short)(u >> 16);
}
__device__ __forceinline__ float bf2f(unsigned short s) {
    unsigned u = ((unsigned)s) << 16;
    return __builtin_bit_cast(float, u);
}
__device__ __forceinline__ float bflo(unsigned u) {           // low bf16 of dword
    return __builtin_bit_cast(float, u << 16);
}
__device__ __forceinline__ float bfhi(unsigned u) {           // high bf16 of dword
    return __builtin_bit_cast(float, u & 0xffff0000u);
}

// token row -> row in d_out ([B, 4165, 512], scales concatenated per batch)
__device__ __forceinline__ int permute_row(int t) {
    int off, area, qoff;
    if (t < 12544)      { off = 0;     area = 3136; qoff = 0;    }
    else if (t < 15680) { off = 12544; area = 784;  qoff = 3136; }
    else if (t < 16464) { off = 15680; area = 196;  qoff = 3920; }
    else                { off = 16464; area = 49;   qoff = 4116; }
    int rel = t - off;
    int b = rel / area;
    int pos = rel - b * area;
    return b * LQTOT + qoff + pos;
}

// token row -> fp32 row pointer inside the 4 concatenated src arrays
__device__ __forceinline__ const float* src_row(int row, const float* s0, const float* s1,
                                                const float* s2, const float* s3) {
    if (row < 12544) return s0 + (size_t)row * 512;
    if (row < 15680) return s1 + (size_t)(row - 12544) * 512;
    if (row < 16464) return s2 + (size_t)(row - 15680) * 512;
    return s3 + (size_t)(row - 16464) * 512;
}

__device__ __forceinline__ void async_copy16(const unsigned short* g, unsigned short* lds_wave_uniform) {
    __builtin_amdgcn_global_load_lds((g_u32*)g, (l_u32*)lds_wave_uniform, 16, 0, 0);
}

// ---------------------------------------------------------------------------
// bf16 MFMA GEMM: C = A[M,Kd] @ (Bt[N,Kd])^T (+bias)(+epilogue)
// 128x128 tile, BK=64 (32 MFMA per barrier pair — halves barrier-drain count
// vs BK=32; TM=64 experiment showed drains-per-MFMA, not occupancy, is the
// limiter). 256 threads = 4 waves (2x2 of 64x64), 16x16x32 MFMA.
// LDS: chunk c of row r at slot c^(r&7) -> staging is linear tid*16 (legal
// for global_load_lds) and fragment ds_read_b128 is 2-way-bank = free.
// ---------------------------------------------------------------------------
enum { EPI_SPLIT = 0, EPI_RESID_SRC = 1, EPI_RELU = 2, EPI_RESID_SCATTER = 3 };

struct GemmArgs {
    const unsigned short* A;    // [Mpad, Kd] bf16
    const unsigned short* Bt;   // [N, Kd]   bf16 (W^T)
    const float* bias0; const float* bias1; const float* bias2;
    const unsigned short* residb;   // bf16 residual (scatter epi)
    const float* s0; const float* s1; const float* s2; const float* s3; // fp32 resid gather
    void* out0; unsigned short* out1; unsigned short* out2;
    int M, N, Kd;
};

template <int EPI>
__global__ __launch_bounds__(256) void gemm_mfma(GemmArgs a)
{
    __shared__ unsigned short As[128 * 64];   // 16 KB
    __shared__ unsigned short Bs[128 * 64];   // 16 KB
    const int tid  = threadIdx.x;
    const int wave = tid >> 6;
    const int lane = tid & 63;
    const int m0 = blockIdx.y * 128;
    const int n0 = blockIdx.x * 128;

    // staging: thread -> row = tid>>3 (+32/pass), chunk kg stored at slot tid&7
    const int srow = tid >> 3;                     // 0..31
    const int kg   = (tid & 7) ^ (srow & 7);       // global k-chunk (8 elem)
    const unsigned short* Ag = a.A  + (size_t)(m0 + srow) * a.Kd + kg * 8;
    const unsigned short* Bg = a.Bt + (size_t)(n0 + srow) * a.Kd + kg * 8;
    const size_t rstep32 = (size_t)32 * a.Kd;
    // LDS dst: pass p, thread t -> bytes p*4096 + t*16 (= wave-uniform + lane*16)
    unsigned short* ldsA = As + wave * 512;
    unsigned short* ldsB = Bs + wave * 512;

    const int wm = (wave >> 1) << 6;
    const int wn = (wave & 1) << 6;
    const int fm = lane & 15;
    const int fq = lane >> 4;
    const int fx7 = fm & 7;

    const f32x4 fzero = {0.f, 0.f, 0.f, 0.f};
    f32x4 acc[4][4];
#pragma unroll
    for (int i = 0; i < 4; ++i)
#pragma unroll
        for (int j = 0; j < 4; ++j) acc[i][j] = fzero;

    for (int k0 = 0; k0 < a.Kd; k0 += 64) {
        __syncthreads();                    // all waves done reading LDS
#pragma unroll
        for (int p = 0; p < 4; ++p) {
            async_copy16(Ag + p * rstep32 + k0, ldsA + p * 2048);
            async_copy16(Bg + p * rstep32 + k0, ldsB + p * 2048);
        }
        __syncthreads();                    // drains vmcnt -> tiles visible
#pragma unroll
        for (int sub = 0; sub < 2; ++sub) {
            const int slot = ((sub * 4 + fq) ^ fx7) << 3;   // ushort offset
            bf16x8 af[4], bfr[4];
#pragma unroll
            for (int mt = 0; mt < 4; ++mt)
                af[mt] = *(const bf16x8*)&As[(wm + mt * 16 + fm) * 64 + slot];
#pragma unroll
            for (int nt = 0; nt < 4; ++nt)
                bfr[nt] = *(const bf16x8*)&Bs[(wn + nt * 16 + fm) * 64 + slot];
#pragma unroll
            for (int mt = 0; mt < 4; ++mt)
#pragma unroll
                for (int nt = 0; nt < 4; ++nt)
                    acc[mt][nt] = __builtin_amdgcn_mfma_f32_16x16x32_bf16(
                        af[mt], bfr[nt], acc[mt][nt], 0, 0, 0);
        }
    }

    // epilogue — C/D layout: col = lane&15, row = (lane>>4)*4 + reg
    const int cn0 = n0 + wn + fm;
    int cols[4]; float bi[4];
#pragma unroll
    for (int nt = 0; nt < 4; ++nt) {
        const int c = cn0 + nt * 16;
        cols[nt] = c;
        if (EPI == EPI_SPLIT)
            bi[nt] = (c < 512) ? a.bias0[c] : (c < 768) ? a.bias1[c - 512] : a.bias2[c - 768];
        else
            bi[nt] = a.bias0[c];
    }
#pragma unroll
    for (int mt = 0; mt < 4; ++mt) {
#pragma unroll
        for (int r = 0; r < 4; ++r) {
            const int row = m0 + wm + mt * 16 + fq * 4 + r;
            if (row >= a.M) continue;
            const size_t ro = (size_t)row;
            const float* srcres = (EPI == EPI_RESID_SRC)
                                  ? src_row(row, a.s0, a.s1, a.s2, a.s3) : nullptr;
#pragma unroll
            for (int nt = 0; nt < 4; ++nt) {
                float v = acc[mt][nt][r] + bi[nt];
                const int c = cols[nt];
                if (EPI == EPI_SPLIT) {
                    if (c < 512)      ((unsigned short*)a.out0)[ro * 512 + c]        = f2bf(v);
                    else if (c < 768) a.out1[ro * 256 + (c - 512)]                   = f2bf(v);
                    else              a.out2[ro * 128 + (c - 768)]                   = f2bf(v);
                } else if (EPI == EPI_RESID_SRC) {
                    v += srcres[c];
                    ((unsigned short*)a.out0)[ro * 512 + c] = f2bf(v);
                } else if (EPI == EPI_RELU) {
                    v = fmaxf(v, 0.f);
                    ((unsigned short*)a.out0)[ro * 2048 + c] = f2bf(v);
                } else { // EPI_RESID_SCATTER
                    v += bf2f(a.residb[ro * 512 + c]);
                    ((float*)a.out0)[(size_t)permute_row(row) * 512 + c] = v;
                }
            }
        }
    }
}

// ---------------------------------------------------------------------------
// prep: all 6 weight transposes (fp32 [K,N] -> bf16 [N,K]) + Q concat in one
// launch. Blocks [0,2752) = 32x32 transpose tiles; [2752,11082) = concat.
// ---------------------------------------------------------------------------
struct PrepArgs {
    const float *Wv, *Woff, *Wattn, *Wo, *W1, *W2;
    unsigned short *Wcat, *Wot, *W1t, *W2t;
    const float *s0, *s1, *s2, *s3;
    unsigned short* Qb;
};

__global__ __launch_bounds__(256) void prep(PrepArgs p)
{
    __shared__ unsigned short t[32][33];
    const int bid = blockIdx.x;
    if (bid < 2752) {
        const float* W; unsigned short* Wt; int K, N, lbx, rel;
        if (bid < 256)       { W = p.Wv;    Wt = p.Wcat;                   K = 512;  N = 512;  lbx = 4; rel = bid; }
        else if (bid < 384)  { W = p.Woff;  Wt = p.Wcat + (size_t)512*512; K = 512;  N = 256;  lbx = 3; rel = bid - 256; }
        else if (bid < 448)  { W = p.Wattn; Wt = p.Wcat + (size_t)768*512; K = 512;  N = 128;  lbx = 2; rel = bid - 384; }
        else if (bid < 704)  { W = p.Wo;    Wt = p.Wot;                    K = 512;  N = 512;  lbx = 4; rel = bid - 448; }
        else if (bid < 1728) { W = p.W1;    Wt = p.W1t;                    K = 512;  N = 2048; lbx = 6; rel = bid - 704; }
        else                 { W = p.W2;    Wt = p.W2t;                    K = 2048; N = 512;  lbx = 4; rel = bid - 1728; }
        const int bx = rel & ((1 << lbx) - 1);
        const int by = rel >> lbx;
        const int tx = threadIdx.x & 31, ty = threadIdx.x >> 5;
        const int nb = bx * 32, kb = by * 32;
#pragma unroll
        for (int j = 0; j < 32; j += 8)
            t[ty + j][tx] = f2bf(W[(size_t)(kb + ty + j) * N + nb + tx]);
        __syncthreads();
#pragma unroll
        for (int j = 0; j < 32; j += 8)
            Wt[(size_t)(nb + ty + j) * K + kb + tx] = t[tx][ty + j];
    } else {
        const int gid = (bid - 2752) * 256 + threadIdx.x;   // over TTOT*128 exactly
        const int e = gid * 4;
        const int row = e >> 9, col = e & 511;
        const float* sr = src_row(row, p.s0, p.s1, p.s2, p.s3);
        const float4 v = *(const float4*)(sr + col);
        ushort4 o;
        o.x = f2bf(v.x); o.y = f2bf(v.y); o.z = f2bf(v.z); o.w = f2bf(v.w);
        *(ushort4*)(p.Qb + (size_t)row * 512 + col) = o;
    }
}

// ---------------------------------------------------------------------------
// deformable sampling v4: block = 2 tokens, 4 waves.
// Phase 1: all 256 threads, thread = (token_local, head, sample); softmax via
//   width-16 shuffles with denom folded into weights; clamped byte indices +
//   validity-zeroed weights -> LDS.
// Phase 2: wave = (token_local, head-quad); lane owns 4 packed bf16 channels
//   (dwordx2 gathers, 8 B/lane), 16 samples x 4 unconditional corners.
// ---------------------------------------------------------------------------
__global__ __launch_bounds__(256) void sample_attn(
    const unsigned short* __restrict__ Vp, const unsigned short* __restrict__ OFFB,
    const unsigned short* __restrict__ ATT,
    const float* __restrict__ rf0, const float* __restrict__ rf1,
    const float* __restrict__ rf2, const float* __restrict__ rf3,
    unsigned short* __restrict__ ACCb)
{
    __shared__ int   midx[2][8][16][4];
    __shared__ float mw[2][8][16][4];
    const int tid = threadIdx.x;

    // ---- phase 1: thread = (tl, h, s) ----
    {
        const int tl = tid >> 7;
        const int h  = (tid >> 4) & 7;
        const int s  = tid & 15;
        const int t  = blockIdx.x * 2 + tl;
        const int li = s >> 2;

        int soff, area;
        const float* rp;
        if (t < 12544)      { soff = 0;     area = 3136; rp = rf0 + (size_t)t * 2; }
        else if (t < 15680) { soff = 12544; area = 784;  rp = rf1 + (size_t)(t - 12544) * 2; }
        else if (t < 16464) { soff = 15680; area = 196;  rp = rf2 + (size_t)(t - 15680) * 2; }
        else                { soff = 16464; area = 49;   rp = rf3 + (size_t)(t - 16464) * 2; }
        const int b = (t - soff) / area;

        // softmax over 16 logits of this head (width-16 shuffle groups)
        float logit = bf2f(ATT[(size_t)t * 128 + h * 16 + s]);
        float mx = logit;
#pragma unroll
        for (int o = 8; o > 0; o >>= 1) mx = fmaxf(mx, __shfl_xor(mx, o, 16));
        float e = __expf(logit - mx);
        float sumv = e;
#pragma unroll
        for (int o = 8; o > 0; o >>= 1) sumv += __shfl_xor(sumv, o, 16);
        const float ew = e / sumv;         // softmax denom folded in

        // coords: (rx + ox/wl)*wl - 0.5 == rx*wl + ox - 0.5
        const int wl = 56 >> li;
        const int lvlbase = (li == 0) ? 0 : (li == 1) ? 12544 : (li == 2) ? 15680 : 16464;
        const int base = lvlbase + b * wl * wl;
        const float rx = rp[0], ry = rp[1];
        const unsigned off2 = *(const unsigned*)(OFFB + (size_t)t * 256 + h * 32 + s * 2);
        const float ox = bflo(off2);
        const float oy = bfhi(off2);
        const float x = rx * (float)wl + ox - 0.5f;
        const float y = ry * (float)wl + oy - 0.5f;
        const float x0f = floorf(x), y0f = floorf(y);
        const float wx1 = x - x0f, wx0 = 1.f - wx1;
        const float wy1 = y - y0f, wy0 = 1.f - wy1;
        const int x0 = (int)x0f, y0 = (int)y0f;
        const int x1 = x0 + 1, y1 = y0 + 1;
        const int xc0 = min(max(x0, 0), wl - 1), xc1 = min(max(x1, 0), wl - 1);
        const int yc0 = min(max(y0, 0), wl - 1), yc1 = min(max(y1, 0), wl - 1);
        const float fx0 = (x0 >= 0 && x0 < wl) ? 1.f : 0.f;
        const float fx1 = (x1 >= 0 && x1 < wl) ? 1.f : 0.f;
        const float fy0 = (y0 >= 0 && y0 < wl) ? 1.f : 0.f;
        const float fy1 = (y1 >= 0 && y1 < wl) ? 1.f : 0.f;
        const int hb2 = h * 128;           // head base, BYTES (64 ch * 2B)
        midx[tl][h][s][0] = (base + yc0 * wl + xc0) * 1024 + hb2;   // *512 elem *2B
        midx[tl][h][s][1] = (base + yc0 * wl + xc1) * 1024 + hb2;
        midx[tl][h][s][2] = (base + yc1 * wl + xc0) * 1024 + hb2;
        midx[tl][h][s][3] = (base + yc1 * wl + xc1) * 1024 + hb2;
        mw[tl][h][s][0] = wx0 * wy0 * fx0 * fy0 * ew;
        mw[tl][h][s][1] = wx1 * wy0 * fx1 * fy0 * ew;
        mw[tl][h][s][2] = wx0 * wy1 * fx0 * fy1 * ew;
        mw[tl][h][s][3] = wx1 * wy1 * fx1 * fy1 * ew;
    }
    __syncthreads();

    // ---- phase 2: wave = (tl, head-quad), lane owns 4 channels ----
    const int wave = tid >> 6;
    const int lane = tid & 63;
    const int tl = wave >> 1;
    const int h  = (wave & 1) * 4 + (lane >> 4);
    const int t  = blockIdx.x * 2 + tl;
    const int off8 = (lane & 15) * 8;      // byte offset within head's 128B row
    const char* vb = (const char*)Vp;
    float a0 = 0.f, a1 = 0.f, a2 = 0.f, a3 = 0.f;
#pragma unroll
    for (int s = 0; s < 16; ++s) {
        const int4   I = *(const int4*)&midx[tl][h][s][0];
        const float4 W = *(const float4*)&mw[tl][h][s][0];
        const uint2 u0 = *(const uint2*)(vb + (I.x + off8));
        const uint2 u1 = *(const uint2*)(vb + (I.y + off8));
        const uint2 u2 = *(const uint2*)(vb + (I.z + off8));
        const uint2 u3 = *(const uint2*)(vb + (I.w + off8));
        a0 += W.x * bflo(u0.x); a1 += W.x * bfhi(u0.x); a2 += W.x * bflo(u0.y); a3 += W.x * bfhi(u0.y);
        a0 += W.y * bflo(u1.x); a1 += W.y * bfhi(u1.x); a2 += W.y * bflo(u1.y); a3 += W.y * bfhi(u1.y);
        a0 += W.z * bflo(u2.x); a1 += W.z * bfhi(u2.x); a2 += W.z * bflo(u2.y); a3 += W.z * bfhi(u2.y);
        a0 += W.w * bflo(u3.x); a1 += W.w * bfhi(u3.x); a2 += W.w * bflo(u3.y); a3 += W.w * bfhi(u3.y);
    }
    ushort4 o;
    o.x = f2bf(a0); o.y = f2bf(a1); o.z = f2bf(a2); o.w = f2bf(a3);
    *(ushort4*)((char*)ACCb + (size_t)t * 1024 + h * 128 + off8) = o;
}

// in-place layernorm on bf16 rows of 512 (fp32 stats)
__global__ __launch_bounds__(256) void ln_bf16(
    unsigned short* __restrict__ X, const float* __restrict__ g, const float* __restrict__ be)
{
    const int row = blockIdx.x;
    unsigned short* xr = X + (size_t)row * 512;
    const int tid = threadIdx.x;
    float v0 = bf2f(xr[tid]);
    float v1 = bf2f(xr[tid + 256]);
    float s = v0 + v1;
    float ss = v0 * v0 + v1 * v1;
#pragma unroll
    for (int o = 32; o > 0; o >>= 1) {
        s += __shfl_down(s, o, 64);
        ss += __shfl_down(ss, o, 64);
    }
    __shared__ float sm[4], sm2[4];
    const int w = tid >> 6;
    if ((tid & 63) == 0) { sm[w] = s; sm2[w] = ss; }
    __syncthreads();
    if (tid == 0) {
        sm[0] = sm[0] + sm[1] + sm[2] + sm[3];
        sm2[0] = sm2[0] + sm2[1] + sm2[2] + sm2[3];
    }
    __syncthreads();
    const float mu = sm[0] * (1.f / 512.f);
    const float var = sm2[0] * (1.f / 512.f) - mu * mu;
    const float rs = rsqrtf(var + 1e-5f);
    xr[tid]       = f2bf((v0 - mu) * rs * g[tid]       + be[tid]);
    xr[tid + 256] = f2bf((v1 - mu) * rs * g[tid + 256] + be[tid + 256]);
}

// in-place fp32 layernorm (final, on d_out)
__global__ __launch_bounds__(256) void ln_f32(
    float* __restrict__ X, const float* __restrict__ g, const float* __restrict__ be)
{
    const int row = blockIdx.x;
    float* xr = X + (size_t)row * 512;
    const int tid = threadIdx.x;
    float v0 = xr[tid];
    float v1 = xr[tid + 256];
    float s = v0 + v1;
    float ss = v0 * v0 + v1 * v1;
#pragma unroll
    for (int o = 32; o > 0; o >>= 1) {
        s += __shfl_down(s, o, 64);
        ss += __shfl_down(ss, o, 64);
    }
    __shared__ float sm[4], sm2[4];
    const int w = tid >> 6;
    if ((tid & 63) == 0) { sm[w] = s; sm2[w] = ss; }
    __syncthreads();
    if (tid == 0) {
        sm[0] = sm[0] + sm[1] + sm[2] + sm[3];
        sm2[0] = sm2[0] + sm2[1] + sm2[2] + sm2[3];
    }
    __syncthreads();
    const float mu = sm[0] * (1.f / 512.f);
    const float var = sm2[0] * (1.f / 512.f) - mu * mu;
    const float rs = rsqrtf(var + 1e-5f);
    xr[tid]       = (v0 - mu) * rs * g[tid]       + be[tid];
    xr[tid + 256] = (v1 - mu) * rs * g[tid + 256] + be[tid + 256];
}

extern "C" void kernel_launch(void* const* d_in, const int* in_sizes, int n_in,
                              void* d_out, int out_size, void* d_ws, size_t ws_size,
                              hipStream_t stream)
{
    const float* src[4] = { (const float*)d_in[0], (const float*)d_in[2],
                            (const float*)d_in[4], (const float*)d_in[6] };
    const float* ref[4] = { (const float*)d_in[1], (const float*)d_in[3],
                            (const float*)d_in[5], (const float*)d_in[7] };
    const float* Wv    = (const float*)d_in[8];
    const float* bv    = (const float*)d_in[9];
    const float* Woff  = (const float*)d_in[10];
    const float* boff  = (const float*)d_in[11];
    const float* Wattn = (const float*)d_in[12];
    const float* battn = (const float*)d_in[13];
    const float* Wo    = (const float*)d_in[14];
    const float* bo    = (const float*)d_in[15];
    const float* W1    = (const float*)d_in[16];
    const float* b1    = (const float*)d_in[17];
    const float* W2    = (const float*)d_in[18];
    const float* b2    = (const float*)d_in[19];
    const float* g1    = (const float*)d_in[20];
    const float* be1   = (const float*)d_in[21];
    const float* g2    = (const float*)d_in[22];
    const float* be2   = (const float*)d_in[23];

    // workspace layout (bf16 == unsigned short)
    unsigned short* w    = (unsigned short*)d_ws;
    unsigned short* Qb   = w;                              // [TPAD,512]
    unsigned short* Vp   = Qb   + (size_t)TPAD * 512;      // [TPAD,512]
    unsigned short* OFFB = Vp   + (size_t)TPAD * 512;      // [TPAD,256]
    unsigned short* ATT  = OFFB + (size_t)TPAD * 256;      // [TPAD,128]
    unsigned short* ACCb = ATT  + (size_t)TPAD * 128;      // [TPAD,512]
    unsigned short* X1b  = ACCb + (size_t)TPAD * 512;      // [TPAD,512]
    unsigned short* Fb   = X1b  + (size_t)TPAD * 512;      // [TPAD,2048]
    unsigned short* Wcat = Fb   + (size_t)TPAD * 2048;     // [896,512]
    unsigned short* Wot  = Wcat + (size_t)896 * 512;       // [512,512]
    unsigned short* W1t  = Wot  + (size_t)512 * 512;       // [2048,512]
    unsigned short* W2t  = W1t  + (size_t)2048 * 512;      // [512,2048]

    const dim3 blk(256);

    PrepArgs pp = {};
    pp.Wv = Wv; pp.Woff = Woff; pp.Wattn = Wattn; pp.Wo = Wo; pp.W1 = W1; pp.W2 = W2;
    pp.Wcat = Wcat; pp.Wot = Wot; pp.W1t = W1t; pp.W2t = W2t;
    pp.s0 = src[0]; pp.s1 = src[1]; pp.s2 = src[2]; pp.s3 = src[3];
    pp.Qb = Qb;
    prep<<<dim3(11082), blk, 0, stream>>>(pp);

    // fused V/off/attn projection: [T,512] @ [512,896]
    GemmArgs a1 = {};
    a1.A = Qb; a1.Bt = Wcat; a1.bias0 = bv; a1.bias1 = boff; a1.bias2 = battn;
    a1.out0 = Vp; a1.out1 = OFFB; a1.out2 = ATT; a1.M = TTOT; a1.N = 896; a1.Kd = 512;
    gemm_mfma<EPI_SPLIT><<<dim3(7, 131), blk, 0, stream>>>(a1);

    sample_attn<<<dim3(TTOT / 2), blk, 0, stream>>>(Vp, OFFB, ATT,
                                                    ref[0], ref[1], ref[2], ref[3], ACCb);

    // output projection + residual(q from srcs)
    GemmArgs a2 = {};
    a2.A = ACCb; a2.Bt = Wot; a2.bias0 = bo;
    a2.s0 = src[0]; a2.s1 = src[1]; a2.s2 = src[2]; a2.s3 = src[3];
    a2.out0 = X1b; a2.M = TTOT; a2.N = 512; a2.Kd = 512;
    gemm_mfma<EPI_RESID_SRC><<<dim3(4, 131), blk, 0, stream>>>(a2);

    ln_bf16<<<dim3(TTOT), blk, 0, stream>>>(X1b, g1, be1);

    // FFN up + relu
    GemmArgs a3 = {};
    a3.A = X1b; a3.Bt = W1t; a3.bias0 = b1;
    a3.out0 = Fb; a3.M = TTOT; a3.N = 2048; a3.Kd = 512;
    gemm_mfma<EPI_RELU><<<dim3(16, 131), blk, 0, stream>>>(a3);

    // FFN down + residual(x) + scatter into d_out layout
    GemmArgs a4 = {};
    a4.A = Fb; a4.Bt = W2t; a4.bias0 = b2; a4.residb = X1b;
    a4.out0 = d_out; a4.M = TTOT; a4.N = 512; a4.Kd = 2048;
    gemm_mfma<EPI_RESID_SCATTER><<<dim3(4, 131), blk, 0, stream>>>(a4);

    ln_f32<<<dim3(TTOT), blk, 0, stream>>>((float*)d_out, g2, be2);
}

// Round 7
// 390.637 us; speedup vs baseline: 1.1282x; 1.0264x over previous
//
#include <hip/hip_runtime.h>
#include <math.h>

// ---------------------------------------------------------------------------
// DETR deformable-transformer encoder layer, MI355X — bf16 MFMA version.
// D=512, H=8, DFF=2048, K=4, S=4, DH=64, B=4
// token counts per scale (incl. batch): 12544, 3136, 784, 196 ; T=16660
// ---------------------------------------------------------------------------

#define TTOT 16660
#define TPAD 16768   // 131 * 128
#define LQTOT 4165

typedef __attribute__((ext_vector_type(8))) short bf16x8;
typedef __attribute__((ext_vector_type(4))) float f32x4;

typedef __attribute__((address_space(1))) const unsigned int g_u32;
typedef __attribute__((address_space(3))) unsigned int l_u32;

__device__ __forceinline__ unsigned short f2bf(float f) {
    unsigned u = __builtin_bit_cast(unsigned, f);
    u += 0x7fffu + ((u >> 16) & 1u);
    return (unsigned short)(u >> 16);
}
__device__ __forceinline__ float bf2f(unsigned short s) {
    unsigned u = ((unsigned)s) << 16;
    return __builtin_bit_cast(float, u);
}
__device__ __forceinline__ float bflo(unsigned u) {           // low bf16 of dword
    return __builtin_bit_cast(float, u << 16);
}
__device__ __forceinline__ float bfhi(unsigned u) {           // high bf16 of dword
    return __builtin_bit_cast(float, u & 0xffff0000u);
}

// token row -> row in d_out ([B, 4165, 512], scales concatenated per batch)
__device__ __forceinline__ int permute_row(int t) {
    int off, area, qoff;
    if (t < 12544)      { off = 0;     area = 3136; qoff = 0;    }
    else if (t < 15680) { off = 12544; area = 784;  qoff = 3136; }
    else if (t < 16464) { off = 15680; area = 196;  qoff = 3920; }
    else                { off = 16464; area = 49;   qoff = 4116; }
    int rel = t - off;
    int b = rel / area;
    int pos = rel - b * area;
    return b * LQTOT + qoff + pos;
}

// token row -> fp32 row pointer inside the 4 concatenated src arrays
__device__ __forceinline__ const float* src_row(int row, const float* s0, const float* s1,
                                                const float* s2, const float* s3) {
    if (row < 12544) return s0 + (size_t)row * 512;
    if (row < 15680) return s1 + (size_t)(row - 12544) * 512;
    if (row < 16464) return s2 + (size_t)(row - 15680) * 512;
    return s3 + (size_t)(row - 16464) * 512;
}

__device__ __forceinline__ void async_copy16(const unsigned short* g, unsigned short* lds_wave_uniform) {
    __builtin_amdgcn_global_load_lds((g_u32*)g, (l_u32*)lds_wave_uniform, 16, 0, 0);
}

// ---------------------------------------------------------------------------
// bf16 MFMA GEMM: C = A[M,Kd] @ (Bt[N,Kd])^T (+bias)(+epilogue)
// 128x128 tile, BK=64 (32 MFMA per barrier pair). 256 threads = 4 waves
// (2x2 of 64x64), 16x16x32 MFMA. LDS: chunk c of row r at slot c^(r&7) ->
// staging is linear tid*16 (legal for global_load_lds) and fragment
// ds_read_b128 is 2-way-bank = free.
// ---------------------------------------------------------------------------
enum { EPI_SPLIT = 0, EPI_RESID_SRC = 1, EPI_RELU = 2, EPI_RESID_SCATTER = 3 };

struct GemmArgs {
    const unsigned short* A;    // [Mpad, Kd] bf16
    const unsigned short* Bt;   // [N, Kd]   bf16 (W^T)
    const float* bias0; const float* bias1; const float* bias2;
    const unsigned short* residb;   // bf16 residual (scatter epi)
    const float* s0; const float* s1; const float* s2; const float* s3; // fp32 resid gather
    void* out0; unsigned short* out1; unsigned short* out2;
    int M, N, Kd;
};

template <int EPI>
__global__ __launch_bounds__(256) void gemm_mfma(GemmArgs a)
{
    __shared__ unsigned short As[128 * 64];   // 16 KB
    __shared__ unsigned short Bs[128 * 64];   // 16 KB
    const int tid  = threadIdx.x;
    const int wave = tid >> 6;
    const int lane = tid & 63;
    const int m0 = blockIdx.y * 128;
    const int n0 = blockIdx.x * 128;

    // staging: thread -> row = tid>>3 (+32/pass), chunk kg stored at slot tid&7
    const int srow = tid >> 3;                     // 0..31
    const int kg   = (tid & 7) ^ (srow & 7);       // global k-chunk (8 elem)
    const unsigned short* Ag = a.A  + (size_t)(m0 + srow) * a.Kd + kg * 8;
    const unsigned short* Bg = a.Bt + (size_t)(n0 + srow) * a.Kd + kg * 8;
    const size_t rstep32 = (size_t)32 * a.Kd;
    unsigned short* ldsA = As + wave * 512;
    unsigned short* ldsB = Bs + wave * 512;

    const int wm = (wave >> 1) << 6;
    const int wn = (wave & 1) << 6;
    const int fm = lane & 15;
    const int fq = lane >> 4;
    const int fx7 = fm & 7;

    const f32x4 fzero = {0.f, 0.f, 0.f, 0.f};
    f32x4 acc[4][4];
#pragma unroll
    for (int i = 0; i < 4; ++i)
#pragma unroll
        for (int j = 0; j < 4; ++j) acc[i][j] = fzero;

    for (int k0 = 0; k0 < a.Kd; k0 += 64) {
        __syncthreads();                    // all waves done reading LDS
#pragma unroll
        for (int p = 0; p < 4; ++p) {
            async_copy16(Ag + p * rstep32 + k0, ldsA + p * 2048);
            async_copy16(Bg + p * rstep32 + k0, ldsB + p * 2048);
        }
        __syncthreads();                    // drains vmcnt -> tiles visible
#pragma unroll
        for (int sub = 0; sub < 2; ++sub) {
            const int slot = ((sub * 4 + fq) ^ fx7) << 3;   // ushort offset
            bf16x8 af[4], bfr[4];
#pragma unroll
            for (int mt = 0; mt < 4; ++mt)
                af[mt] = *(const bf16x8*)&As[(wm + mt * 16 + fm) * 64 + slot];
#pragma unroll
            for (int nt = 0; nt < 4; ++nt)
                bfr[nt] = *(const bf16x8*)&Bs[(wn + nt * 16 + fm) * 64 + slot];
#pragma unroll
            for (int mt = 0; mt < 4; ++mt)
#pragma unroll
                for (int nt = 0; nt < 4; ++nt)
                    acc[mt][nt] = __builtin_amdgcn_mfma_f32_16x16x32_bf16(
                        af[mt], bfr[nt], acc[mt][nt], 0, 0, 0);
        }
    }

    // epilogue — C/D layout: col = lane&15, row = (lane>>4)*4 + reg
    const int cn0 = n0 + wn + fm;
    int cols[4]; float bi[4];
#pragma unroll
    for (int nt = 0; nt < 4; ++nt) {
        const int c = cn0 + nt * 16;
        cols[nt] = c;
        if (EPI == EPI_SPLIT)
            bi[nt] = (c < 512) ? a.bias0[c] : (c < 768) ? a.bias1[c - 512] : a.bias2[c - 768];
        else
            bi[nt] = a.bias0[c];
    }
#pragma unroll
    for (int mt = 0; mt < 4; ++mt) {
#pragma unroll
        for (int r = 0; r < 4; ++r) {
            const int row = m0 + wm + mt * 16 + fq * 4 + r;
            if (row >= a.M) continue;
            const size_t ro = (size_t)row;
            const float* srcres = (EPI == EPI_RESID_SRC)
                                  ? src_row(row, a.s0, a.s1, a.s2, a.s3) : nullptr;
#pragma unroll
            for (int nt = 0; nt < 4; ++nt) {
                float v = acc[mt][nt][r] + bi[nt];
                const int c = cols[nt];
                if (EPI == EPI_SPLIT) {
                    if (c < 512)      ((unsigned short*)a.out0)[ro * 512 + c]        = f2bf(v);
                    else if (c < 768) a.out1[ro * 256 + (c - 512)]                   = f2bf(v);
                    else              a.out2[ro * 128 + (c - 768)]                   = f2bf(v);
                } else if (EPI == EPI_RESID_SRC) {
                    v += srcres[c];
                    ((unsigned short*)a.out0)[ro * 512 + c] = f2bf(v);
                } else if (EPI == EPI_RELU) {
                    v = fmaxf(v, 0.f);
                    ((unsigned short*)a.out0)[ro * 2048 + c] = f2bf(v);
                } else { // EPI_RESID_SCATTER
                    v += bf2f(a.residb[ro * 512 + c]);
                    ((float*)a.out0)[(size_t)permute_row(row) * 512 + c] = v;
                }
            }
        }
    }
}

// ---------------------------------------------------------------------------
// prep: all 6 weight transposes (fp32 [K,N] -> bf16 [N,K]) + Q concat in one
// launch. Blocks [0,2752) = 32x32 transpose tiles; [2752,11082) = concat.
// ---------------------------------------------------------------------------
struct PrepArgs {
    const float *Wv, *Woff, *Wattn, *Wo, *W1, *W2;
    unsigned short *Wcat, *Wot, *W1t, *W2t;
    const float *s0, *s1, *s2, *s3;
    unsigned short* Qb;
};

__global__ __launch_bounds__(256) void prep(PrepArgs p)
{
    __shared__ unsigned short t[32][33];
    const int bid = blockIdx.x;
    if (bid < 2752) {
        const float* W; unsigned short* Wt; int K, N, lbx, rel;
        if (bid < 256)       { W = p.Wv;    Wt = p.Wcat;                   K = 512;  N = 512;  lbx = 4; rel = bid; }
        else if (bid < 384)  { W = p.Woff;  Wt = p.Wcat + (size_t)512*512; K = 512;  N = 256;  lbx = 3; rel = bid - 256; }
        else if (bid < 448)  { W = p.Wattn; Wt = p.Wcat + (size_t)768*512; K = 512;  N = 128;  lbx = 2; rel = bid - 384; }
        else if (bid < 704)  { W = p.Wo;    Wt = p.Wot;                    K = 512;  N = 512;  lbx = 4; rel = bid - 448; }
        else if (bid < 1728) { W = p.W1;    Wt = p.W1t;                    K = 512;  N = 2048; lbx = 6; rel = bid - 704; }
        else                 { W = p.W2;    Wt = p.W2t;                    K = 2048; N = 512;  lbx = 4; rel = bid - 1728; }
        const int bx = rel & ((1 << lbx) - 1);
        const int by = rel >> lbx;
        const int tx = threadIdx.x & 31, ty = threadIdx.x >> 5;
        const int nb = bx * 32, kb = by * 32;
#pragma unroll
        for (int j = 0; j < 32; j += 8)
            t[ty + j][tx] = f2bf(W[(size_t)(kb + ty + j) * N + nb + tx]);
        __syncthreads();
#pragma unroll
        for (int j = 0; j < 32; j += 8)
            Wt[(size_t)(nb + ty + j) * K + kb + tx] = t[tx][ty + j];
    } else {
        const int gid = (bid - 2752) * 256 + threadIdx.x;   // over TTOT*128 exactly
        const int e = gid * 4;
        const int row = e >> 9, col = e & 511;
        const float* sr = src_row(row, p.s0, p.s1, p.s2, p.s3);
        const float4 v = *(const float4*)(sr + col);
        ushort4 o;
        o.x = f2bf(v.x); o.y = f2bf(v.y); o.z = f2bf(v.z); o.w = f2bf(v.w);
        *(ushort4*)(p.Qb + (size_t)row * 512 + col) = o;
    }
}

// ---------------------------------------------------------------------------
// deformable sampling v5: block = 4 tokens, 4 waves; wave = one token.
// Phase 1: 512 (tl,h,s) slots on 256 threads (2 each); softmax via width-16
//   shuffles with denom folded into weights; clamped byte indices +
//   validity-zeroed weights -> LDS, sample dim padded 16->17 so the 8
//   per-head meta groups land on distinct bank quads (conflict-free).
// Phase 2: 8 lanes per head, lane owns 8 packed bf16 channels (dwordx4
//   gathers, 16 B/lane), 16 samples x 4 unconditional corners.
// ---------------------------------------------------------------------------
__global__ __launch_bounds__(256) void sample_attn(
    const unsigned short* __restrict__ Vp, const unsigned short* __restrict__ OFFB,
    const unsigned short* __restrict__ ATT,
    const float* __restrict__ rf0, const float* __restrict__ rf1,
    const float* __restrict__ rf2, const float* __restrict__ rf3,
    unsigned short* __restrict__ ACCb)
{
    __shared__ int   midx[4][8][17][4];   // 8704 B
    __shared__ float mw[4][8][17][4];     // 8704 B
    const int tid = threadIdx.x;

    // ---- phase 1: 2 slots per thread; slot = (tl, h, s) ----
#pragma unroll
    for (int i = 0; i < 2; ++i) {
        const int slot = i * 256 + tid;
        const int tl = slot >> 7;          // 0..3
        const int h  = (slot >> 4) & 7;
        const int s  = slot & 15;
        const int t  = blockIdx.x * 4 + tl;
        const int li = s >> 2;

        int soff, area;
        const float* rp;
        if (t < 12544)      { soff = 0;     area = 3136; rp = rf0 + (size_t)t * 2; }
        else if (t < 15680) { soff = 12544; area = 784;  rp = rf1 + (size_t)(t - 12544) * 2; }
        else if (t < 16464) { soff = 15680; area = 196;  rp = rf2 + (size_t)(t - 15680) * 2; }
        else                { soff = 16464; area = 49;   rp = rf3 + (size_t)(t - 16464) * 2; }
        const int b = (t - soff) / area;

        // softmax over 16 logits of this head (width-16 shuffle groups)
        float logit = bf2f(ATT[(size_t)t * 128 + h * 16 + s]);
        float mx = logit;
#pragma unroll
        for (int o = 8; o > 0; o >>= 1) mx = fmaxf(mx, __shfl_xor(mx, o, 16));
        float e = __expf(logit - mx);
        float sumv = e;
#pragma unroll
        for (int o = 8; o > 0; o >>= 1) sumv += __shfl_xor(sumv, o, 16);
        const float ew = e / sumv;         // softmax denom folded in

        // coords: (rx + ox/wl)*wl - 0.5 == rx*wl + ox - 0.5
        const int wl = 56 >> li;
        const int lvlbase = (li == 0) ? 0 : (li == 1) ? 12544 : (li == 2) ? 15680 : 16464;
        const int base = lvlbase + b * wl * wl;
        const float rx = rp[0], ry = rp[1];
        const unsigned off2 = *(const unsigned*)(OFFB + (size_t)t * 256 + h * 32 + s * 2);
        const float ox = bflo(off2);
        const float oy = bfhi(off2);
        const float x = rx * (float)wl + ox - 0.5f;
        const float y = ry * (float)wl + oy - 0.5f;
        const float x0f = floorf(x), y0f = floorf(y);
        const float wx1 = x - x0f, wx0 = 1.f - wx1;
        const float wy1 = y - y0f, wy0 = 1.f - wy1;
        const int x0 = (int)x0f, y0 = (int)y0f;
        const int x1 = x0 + 1, y1 = y0 + 1;
        const int xc0 = min(max(x0, 0), wl - 1), xc1 = min(max(x1, 0), wl - 1);
        const int yc0 = min(max(y0, 0), wl - 1), yc1 = min(max(y1, 0), wl - 1);
        const float fx0 = (x0 >= 0 && x0 < wl) ? 1.f : 0.f;
        const float fx1 = (x1 >= 0 && x1 < wl) ? 1.f : 0.f;
        const float fy0 = (y0 >= 0 && y0 < wl) ? 1.f : 0.f;
        const float fy1 = (y1 >= 0 && y1 < wl) ? 1.f : 0.f;
        const int hb2 = h * 128;           // head base, BYTES (64 ch * 2B)
        int4 I;
        I.x = (base + yc0 * wl + xc0) * 1024 + hb2;   // *512 elem *2B
        I.y = (base + yc0 * wl + xc1) * 1024 + hb2;
        I.z = (base + yc1 * wl + xc0) * 1024 + hb2;
        I.w = (base + yc1 * wl + xc1) * 1024 + hb2;
        float4 Wt;
        Wt.x = wx0 * wy0 * fx0 * fy0 * ew;
        Wt.y = wx1 * wy0 * fx1 * fy0 * ew;
        Wt.z = wx0 * wy1 * fx0 * fy1 * ew;
        Wt.w = wx1 * wy1 * fx1 * fy1 * ew;
        *(int4*)&midx[tl][h][s][0] = I;
        *(float4*)&mw[tl][h][s][0] = Wt;
    }
    __syncthreads();

    // ---- phase 2: wave = token, 8 lanes/head, lane owns 8 channels ----
    const int wave = tid >> 6;
    const int lane = tid & 63;
    const int tl = wave;
    const int h  = lane >> 3;
    const int t  = blockIdx.x * 4 + tl;
    const int off16 = (lane & 7) * 16;     // byte offset within 128B head row
    const char* vb = (const char*)Vp;
    float a0 = 0.f, a1 = 0.f, a2 = 0.f, a3 = 0.f;
    float a4 = 0.f, a5 = 0.f, a6 = 0.f, a7 = 0.f;
#pragma unroll
    for (int s = 0; s < 16; ++s) {
        const int4   I = *(const int4*)&midx[tl][h][s][0];
        const float4 W = *(const float4*)&mw[tl][h][s][0];
        const uint4 u0 = *(const uint4*)(vb + (I.x + off16));
        const uint4 u1 = *(const uint4*)(vb + (I.y + off16));
        const uint4 u2 = *(const uint4*)(vb + (I.z + off16));
        const uint4 u3 = *(const uint4*)(vb + (I.w + off16));
        a0 += W.x * bflo(u0.x); a1 += W.x * bfhi(u0.x); a2 += W.x * bflo(u0.y); a3 += W.x * bfhi(u0.y);
        a4 += W.x * bflo(u0.z); a5 += W.x * bfhi(u0.z); a6 += W.x * bflo(u0.w); a7 += W.x * bfhi(u0.w);
        a0 += W.y * bflo(u1.x); a1 += W.y * bfhi(u1.x); a2 += W.y * bflo(u1.y); a3 += W.y * bfhi(u1.y);
        a4 += W.y * bflo(u1.z); a5 += W.y * bfhi(u1.z); a6 += W.y * bflo(u1.w); a7 += W.y * bfhi(u1.w);
        a0 += W.z * bflo(u2.x); a1 += W.z * bfhi(u2.x); a2 += W.z * bflo(u2.y); a3 += W.z * bfhi(u2.y);
        a4 += W.z * bflo(u2.z); a5 += W.z * bfhi(u2.z); a6 += W.z * bflo(u2.w); a7 += W.z * bfhi(u2.w);
        a0 += W.w * bflo(u3.x); a1 += W.w * bfhi(u3.x); a2 += W.w * bflo(u3.y); a3 += W.w * bfhi(u3.y);
        a4 += W.w * bflo(u3.z); a5 += W.w * bfhi(u3.z); a6 += W.w * bflo(u3.w); a7 += W.w * bfhi(u3.w);
    }
    uint4 o;
    o.x = ((unsigned)f2bf(a1) << 16) | f2bf(a0);
    o.y = ((unsigned)f2bf(a3) << 16) | f2bf(a2);
    o.z = ((unsigned)f2bf(a5) << 16) | f2bf(a4);
    o.w = ((unsigned)f2bf(a7) << 16) | f2bf(a6);
    *(uint4*)((char*)ACCb + (size_t)t * 1024 + h * 128 + off16) = o;
}

// in-place layernorm on bf16 rows of 512 (fp32 stats)
__global__ __launch_bounds__(256) void ln_bf16(
    unsigned short* __restrict__ X, const float* __restrict__ g, const float* __restrict__ be)
{
    const int row = blockIdx.x;
    unsigned short* xr = X + (size_t)row * 512;
    const int tid = threadIdx.x;
    float v0 = bf2f(xr[tid]);
    float v1 = bf2f(xr[tid + 256]);
    float s = v0 + v1;
    float ss = v0 * v0 + v1 * v1;
#pragma unroll
    for (int o = 32; o > 0; o >>= 1) {
        s += __shfl_down(s, o, 64);
        ss += __shfl_down(ss, o, 64);
    }
    __shared__ float sm[4], sm2[4];
    const int w = tid >> 6;
    if ((tid & 63) == 0) { sm[w] = s; sm2[w] = ss; }
    __syncthreads();
    if (tid == 0) {
        sm[0] = sm[0] + sm[1] + sm[2] + sm[3];
        sm2[0] = sm2[0] + sm2[1] + sm2[2] + sm2[3];
    }
    __syncthreads();
    const float mu = sm[0] * (1.f / 512.f);
    const float var = sm2[0] * (1.f / 512.f) - mu * mu;
    const float rs = rsqrtf(var + 1e-5f);
    xr[tid]       = f2bf((v0 - mu) * rs * g[tid]       + be[tid]);
    xr[tid + 256] = f2bf((v1 - mu) * rs * g[tid + 256] + be[tid + 256]);
}

// in-place fp32 layernorm (final, on d_out)
__global__ __launch_bounds__(256) void ln_f32(
    float* __restrict__ X, const float* __restrict__ g, const float* __restrict__ be)
{
    const int row = blockIdx.x;
    float* xr = X + (size_t)row * 512;
    const int tid = threadIdx.x;
    float v0 = xr[tid];
    float v1 = xr[tid + 256];
    float s = v0 + v1;
    float ss = v0 * v0 + v1 * v1;
#pragma unroll
    for (int o = 32; o > 0; o >>= 1) {
        s += __shfl_down(s, o, 64);
        ss += __shfl_down(ss, o, 64);
    }
    __shared__ float sm[4], sm2[4];
    const int w = tid >> 6;
    if ((tid & 63) == 0) { sm[w] = s; sm2[w] = ss; }
    __syncthreads();
    if (tid == 0) {
        sm[0] = sm[0] + sm[1] + sm[2] + sm[3];
        sm2[0] = sm2[0] + sm2[1] + sm2[2] + sm2[3];
    }
    __syncthreads();
    const float mu = sm[0] * (1.f / 512.f);
    const float var = sm2[0] * (1.f / 512.f) - mu * mu;
    const float rs = rsqrtf(var + 1e-5f);
    xr[tid]       = (v0 - mu) * rs * g[tid]       + be[tid];
    xr[tid + 256] = (v1 - mu) * rs * g[tid + 256] + be[tid + 256];
}

extern "C" void kernel_launch(void* const* d_in, const int* in_sizes, int n_in,
                              void* d_out, int out_size, void* d_ws, size_t ws_size,
                              hipStream_t stream)
{
    const float* src[4] = { (const float*)d_in[0], (const float*)d_in[2],
                            (const float*)d_in[4], (const float*)d_in[6] };
    const float* ref[4] = { (const float*)d_in[1], (const float*)d_in[3],
                            (const float*)d_in[5], (const float*)d_in[7] };
    const float* Wv    = (const float*)d_in[8];
    const float* bv    = (const float*)d_in[9];
    const float* Woff  = (const float*)d_in[10];
    const float* boff  = (const float*)d_in[11];
    const float* Wattn = (const float*)d_in[12];
    const float* battn = (const float*)d_in[13];
    const float* Wo    = (const float*)d_in[14];
    const float* bo    = (const float*)d_in[15];
    const float* W1    = (const float*)d_in[16];
    const float* b1    = (const float*)d_in[17];
    const float* W2    = (const float*)d_in[18];
    const float* b2    = (const float*)d_in[19];
    const float* g1    = (const float*)d_in[20];
    const float* be1   = (const float*)d_in[21];
    const float* g2    = (const float*)d_in[22];
    const float* be2   = (const float*)d_in[23];

    // workspace layout (bf16 == unsigned short)
    unsigned short* w    = (unsigned short*)d_ws;
    unsigned short* Qb   = w;                              // [TPAD,512]
    unsigned short* Vp   = Qb   + (size_t)TPAD * 512;      // [TPAD,512]
    unsigned short* OFFB = Vp   + (size_t)TPAD * 512;      // [TPAD,256]
    unsigned short* ATT  = OFFB + (size_t)TPAD * 256;      // [TPAD,128]
    unsigned short* ACCb = ATT  + (size_t)TPAD * 128;      // [TPAD,512]
    unsigned short* X1b  = ACCb + (size_t)TPAD * 512;      // [TPAD,512]
    unsigned short* Fb   = X1b  + (size_t)TPAD * 512;      // [TPAD,2048]
    unsigned short* Wcat = Fb   + (size_t)TPAD * 2048;     // [896,512]
    unsigned short* Wot  = Wcat + (size_t)896 * 512;       // [512,512]
    unsigned short* W1t  = Wot  + (size_t)512 * 512;       // [2048,512]
    unsigned short* W2t  = W1t  + (size_t)2048 * 512;      // [512,2048]

    const dim3 blk(256);

    PrepArgs pp = {};
    pp.Wv = Wv; pp.Woff = Woff; pp.Wattn = Wattn; pp.Wo = Wo; pp.W1 = W1; pp.W2 = W2;
    pp.Wcat = Wcat; pp.Wot = Wot; pp.W1t = W1t; pp.W2t = W2t;
    pp.s0 = src[0]; pp.s1 = src[1]; pp.s2 = src[2]; pp.s3 = src[3];
    pp.Qb = Qb;
    prep<<<dim3(11082), blk, 0, stream>>>(pp);

    // fused V/off/attn projection: [T,512] @ [512,896]
    GemmArgs a1 = {};
    a1.A = Qb; a1.Bt = Wcat; a1.bias0 = bv; a1.bias1 = boff; a1.bias2 = battn;
    a1.out0 = Vp; a1.out1 = OFFB; a1.out2 = ATT; a1.M = TTOT; a1.N = 896; a1.Kd = 512;
    gemm_mfma<EPI_SPLIT><<<dim3(7, 131), blk, 0, stream>>>(a1);

    sample_attn<<<dim3(TTOT / 4), blk, 0, stream>>>(Vp, OFFB, ATT,
                                                    ref[0], ref[1], ref[2], ref[3], ACCb);

    // output projection + residual(q from srcs)
    GemmArgs a2 = {};
    a2.A = ACCb; a2.Bt = Wot; a2.bias0 = bo;
    a2.s0 = src[0]; a2.s1 = src[1]; a2.s2 = src[2]; a2.s3 = src[3];
    a2.out0 = X1b; a2.M = TTOT; a2.N = 512; a2.Kd = 512;
    gemm_mfma<EPI_RESID_SRC><<<dim3(4, 131), blk, 0, stream>>>(a2);

    ln_bf16<<<dim3(TTOT), blk, 0, stream>>>(X1b, g1, be1);

    // FFN up + relu
    GemmArgs a3 = {};
    a3.A = X1b; a3.Bt = W1t; a3.bias0 = b1;
    a3.out0 = Fb; a3.M = TTOT; a3.N = 2048; a3.Kd = 512;
    gemm_mfma<EPI_RELU><<<dim3(16, 131), blk, 0, stream>>>(a3);

    // FFN down + residual(x) + scatter into d_out layout
    GemmArgs a4 = {};
    a4.A = Fb; a4.Bt = W2t; a4.bias0 = b2; a4.residb = X1b;
    a4.out0 = d_out; a4.M = TTOT; a4.N = 512; a4.Kd = 2048;
    gemm_mfma<EPI_RESID_SCATTER><<<dim3(4, 131), blk, 0, stream>>>(a4);

    ln_f32<<<dim3(TTOT), blk, 0, stream>>>((float*)d_out, g2, be2);
}

// Round 8
// 389.392 us; speedup vs baseline: 1.1318x; 1.0032x over previous
//
#include <hip/hip_runtime.h>
#include <math.h>

// ---------------------------------------------------------------------------
// DETR deformable-transformer encoder layer, MI355X — bf16 MFMA version.
// D=512, H=8, DFF=2048, K=4, S=4, DH=64, B=4
// token counts per scale (incl. batch): 12544, 3136, 784, 196 ; T=16660
// ---------------------------------------------------------------------------

#define TTOT 16660
#define TPAD 16768   // 131 * 128
#define LQTOT 4165

typedef __attribute__((ext_vector_type(8))) short bf16x8;
typedef __attribute__((ext_vector_type(4))) float f32x4;

typedef __attribute__((address_space(1))) const unsigned int g_u32;
typedef __attribute__((address_space(3))) unsigned int l_u32;

__device__ __forceinline__ unsigned short f2bf(float f) {
    unsigned u = __builtin_bit_cast(unsigned, f);
    u += 0x7fffu + ((u >> 16) & 1u);
    return (unsigned short)(u >> 16);
}
__device__ __forceinline__ float bf2f(unsigned short s) {
    unsigned u = ((unsigned)s) << 16;
    return __builtin_bit_cast(float, u);
}
__device__ __forceinline__ float bflo(unsigned u) {           // low bf16 of dword
    return __builtin_bit_cast(float, u << 16);
}
__device__ __forceinline__ float bfhi(unsigned u) {           // high bf16 of dword
    return __builtin_bit_cast(float, u & 0xffff0000u);
}

// token row -> row in d_out ([B, 4165, 512], scales concatenated per batch)
__device__ __forceinline__ int permute_row(int t) {
    int off, area, qoff;
    if (t < 12544)      { off = 0;     area = 3136; qoff = 0;    }
    else if (t < 15680) { off = 12544; area = 784;  qoff = 3136; }
    else if (t < 16464) { off = 15680; area = 196;  qoff = 3920; }
    else                { off = 16464; area = 49;   qoff = 4116; }
    int rel = t - off;
    int b = rel / area;
    int pos = rel - b * area;
    return b * LQTOT + qoff + pos;
}

// output row r -> token row t (inverse of permute_row)
__device__ __forceinline__ int inv_permute_row(int r) {
    int b = r / LQTOT;
    int pos = r - b * LQTOT;
    int off, area, qoff;
    if (pos < 3136)      { off = 0;     area = 3136; qoff = 0;    }
    else if (pos < 3920) { off = 12544; area = 784;  qoff = 3136; }
    else if (pos < 4116) { off = 15680; area = 196;  qoff = 3920; }
    else                 { off = 16464; area = 49;   qoff = 4116; }
    return off + b * area + (pos - qoff);
}

// token row -> fp32 row pointer inside the 4 concatenated src arrays
__device__ __forceinline__ const float* src_row(int row, const float* s0, const float* s1,
                                                const float* s2, const float* s3) {
    if (row < 12544) return s0 + (size_t)row * 512;
    if (row < 15680) return s1 + (size_t)(row - 12544) * 512;
    if (row < 16464) return s2 + (size_t)(row - 15680) * 512;
    return s3 + (size_t)(row - 16464) * 512;
}

__device__ __forceinline__ void async_copy16(const unsigned short* g, unsigned short* lds_wave_uniform) {
    __builtin_amdgcn_global_load_lds((g_u32*)g, (l_u32*)lds_wave_uniform, 16, 0, 0);
}

// ---------------------------------------------------------------------------
// bf16 MFMA GEMM: C = A[M, lda-strided rows] @ (Bt[N, ldb-strided rows])^T
// 128x128 tile, BK=64 (32 MFMA per barrier pair). 256 threads = 4 waves
// (2x2 of 64x64), 16x16x32 MFMA. LDS: chunk c of row r at slot c^(r&7).
// Split-K via blockIdx.z: block kc processes K-window [kc*Kd, (kc+1)*Kd);
// EPI_PART writes fp32 partial tiles (kc0 -> out0 with bias, kc1 -> out0b
// without bias), both scattered to permuted rows; reduce+LN happens later.
// ---------------------------------------------------------------------------
enum { EPI_SPLIT = 0, EPI_RESID_SRC = 1, EPI_RELU = 2, EPI_PART = 3 };

struct GemmArgs {
    const unsigned short* A;    // [Mpad rows, lda] bf16
    const unsigned short* Bt;   // [N rows, ldb]   bf16 (W^T)
    const float* bias0; const float* bias1; const float* bias2;
    const float* s0; const float* s1; const float* s2; const float* s3; // fp32 resid gather
    void* out0; unsigned short* out1; unsigned short* out2;
    void* out0b;                // EPI_PART kc=1 output
    int M, N, Kd;               // Kd = K-length per block
    int lda, ldb;               // row strides (elements)
};

template <int EPI>
__global__ __launch_bounds__(256) void gemm_mfma(GemmArgs a)
{
    __shared__ unsigned short As[128 * 64];   // 16 KB
    __shared__ unsigned short Bs[128 * 64];   // 16 KB
    const int tid  = threadIdx.x;
    const int wave = tid >> 6;
    const int lane = tid & 63;
    const int m0 = blockIdx.y * 128;
    const int n0 = blockIdx.x * 128;
    const int kc = blockIdx.z;

    // staging: thread -> row = tid>>3 (+32/pass), chunk kg stored at slot tid&7
    const int srow = tid >> 3;                     // 0..31
    const int kg   = (tid & 7) ^ (srow & 7);       // k-chunk (8 elem) within BK
    const unsigned short* Ag = a.A  + (size_t)kc * a.Kd
                             + (size_t)(m0 + srow) * a.lda + kg * 8;
    const unsigned short* Bg = a.Bt + (size_t)kc * a.Kd
                             + (size_t)(n0 + srow) * a.ldb + kg * 8;
    const size_t rstepA = (size_t)32 * a.lda;
    const size_t rstepB = (size_t)32 * a.ldb;
    unsigned short* ldsA = As + wave * 512;
    unsigned short* ldsB = Bs + wave * 512;

    const int wm = (wave >> 1) << 6;
    const int wn = (wave & 1) << 6;
    const int fm = lane & 15;
    const int fq = lane >> 4;
    const int fx7 = fm & 7;

    const f32x4 fzero = {0.f, 0.f, 0.f, 0.f};
    f32x4 acc[4][4];
#pragma unroll
    for (int i = 0; i < 4; ++i)
#pragma unroll
        for (int j = 0; j < 4; ++j) acc[i][j] = fzero;

    for (int k0 = 0; k0 < a.Kd; k0 += 64) {
        __syncthreads();                    // all waves done reading LDS
#pragma unroll
        for (int p = 0; p < 4; ++p) {
            async_copy16(Ag + p * rstepA + k0, ldsA + p * 2048);
            async_copy16(Bg + p * rstepB + k0, ldsB + p * 2048);
        }
        __syncthreads();                    // drains vmcnt -> tiles visible
#pragma unroll
        for (int sub = 0; sub < 2; ++sub) {
            const int slot = ((sub * 4 + fq) ^ fx7) << 3;   // ushort offset
            bf16x8 af[4], bfr[4];
#pragma unroll
            for (int mt = 0; mt < 4; ++mt)
                af[mt] = *(const bf16x8*)&As[(wm + mt * 16 + fm) * 64 + slot];
#pragma unroll
            for (int nt = 0; nt < 4; ++nt)
                bfr[nt] = *(const bf16x8*)&Bs[(wn + nt * 16 + fm) * 64 + slot];
#pragma unroll
            for (int mt = 0; mt < 4; ++mt)
#pragma unroll
                for (int nt = 0; nt < 4; ++nt)
                    acc[mt][nt] = __builtin_amdgcn_mfma_f32_16x16x32_bf16(
                        af[mt], bfr[nt], acc[mt][nt], 0, 0, 0);
        }
    }

    // epilogue — C/D layout: col = lane&15, row = (lane>>4)*4 + reg
    const int cn0 = n0 + wn + fm;
    int cols[4]; float bi[4];
#pragma unroll
    for (int nt = 0; nt < 4; ++nt) {
        const int c = cn0 + nt * 16;
        cols[nt] = c;
        if (EPI == EPI_SPLIT)
            bi[nt] = (c < 512) ? a.bias0[c] : (c < 768) ? a.bias1[c - 512] : a.bias2[c - 768];
        else
            bi[nt] = a.bias0[c];
    }
    if (EPI == EPI_PART && kc != 0) {
#pragma unroll
        for (int nt = 0; nt < 4; ++nt) bi[nt] = 0.f;   // bias only once (kc0)
    }
    float* pout = (EPI == EPI_PART)
                ? (float*)(kc ? a.out0b : a.out0) : nullptr;
#pragma unroll
    for (int mt = 0; mt < 4; ++mt) {
#pragma unroll
        for (int r = 0; r < 4; ++r) {
            const int row = m0 + wm + mt * 16 + fq * 4 + r;
            if (row >= a.M) continue;
            const size_t ro = (size_t)row;
            const float* srcres = (EPI == EPI_RESID_SRC)
                                  ? src_row(row, a.s0, a.s1, a.s2, a.s3) : nullptr;
            const size_t po = (EPI == EPI_PART) ? (size_t)permute_row(row) : 0;
#pragma unroll
            for (int nt = 0; nt < 4; ++nt) {
                float v = acc[mt][nt][r] + bi[nt];
                const int c = cols[nt];
                if (EPI == EPI_SPLIT) {
                    if (c < 512)      ((unsigned short*)a.out0)[ro * 512 + c]        = f2bf(v);
                    else if (c < 768) a.out1[ro * 256 + (c - 512)]                   = f2bf(v);
                    else              a.out2[ro * 128 + (c - 768)]                   = f2bf(v);
                } else if (EPI == EPI_RESID_SRC) {
                    v += srcres[c];
                    ((unsigned short*)a.out0)[ro * 512 + c] = f2bf(v);
                } else if (EPI == EPI_RELU) {
                    v = fmaxf(v, 0.f);
                    ((unsigned short*)a.out0)[ro * 2048 + c] = f2bf(v);
                } else { // EPI_PART
                    pout[po * 512 + c] = v;
                }
            }
        }
    }
}

// ---------------------------------------------------------------------------
// prep: all 6 weight transposes (fp32 [K,N] -> bf16 [N,K]) + Q concat in one
// launch. Blocks [0,2752) = 32x32 transpose tiles; [2752,11082) = concat.
// ---------------------------------------------------------------------------
struct PrepArgs {
    const float *Wv, *Woff, *Wattn, *Wo, *W1, *W2;
    unsigned short *Wcat, *Wot, *W1t, *W2t;
    const float *s0, *s1, *s2, *s3;
    unsigned short* Qb;
};

__global__ __launch_bounds__(256) void prep(PrepArgs p)
{
    __shared__ unsigned short t[32][33];
    const int bid = blockIdx.x;
    if (bid < 2752) {
        const float* W; unsigned short* Wt; int K, N, lbx, rel;
        if (bid < 256)       { W = p.Wv;    Wt = p.Wcat;                   K = 512;  N = 512;  lbx = 4; rel = bid; }
        else if (bid < 384)  { W = p.Woff;  Wt = p.Wcat + (size_t)512*512; K = 512;  N = 256;  lbx = 3; rel = bid - 256; }
        else if (bid < 448)  { W = p.Wattn; Wt = p.Wcat + (size_t)768*512; K = 512;  N = 128;  lbx = 2; rel = bid - 384; }
        else if (bid < 704)  { W = p.Wo;    Wt = p.Wot;                    K = 512;  N = 512;  lbx = 4; rel = bid - 448; }
        else if (bid < 1728) { W = p.W1;    Wt = p.W1t;                    K = 512;  N = 2048; lbx = 6; rel = bid - 704; }
        else                 { W = p.W2;    Wt = p.W2t;                    K = 2048; N = 512;  lbx = 4; rel = bid - 1728; }
        const int bx = rel & ((1 << lbx) - 1);
        const int by = rel >> lbx;
        const int tx = threadIdx.x & 31, ty = threadIdx.x >> 5;
        const int nb = bx * 32, kb = by * 32;
#pragma unroll
        for (int j = 0; j < 32; j += 8)
            t[ty + j][tx] = f2bf(W[(size_t)(kb + ty + j) * N + nb + tx]);
        __syncthreads();
#pragma unroll
        for (int j = 0; j < 32; j += 8)
            Wt[(size_t)(nb + ty + j) * K + kb + tx] = t[tx][ty + j];
    } else {
        const int gid = (bid - 2752) * 256 + threadIdx.x;   // over TTOT*128 exactly
        const int e = gid * 4;
        const int row = e >> 9, col = e & 511;
        const float* sr = src_row(row, p.s0, p.s1, p.s2, p.s3);
        const float4 v = *(const float4*)(sr + col);
        ushort4 o;
        o.x = f2bf(v.x); o.y = f2bf(v.y); o.z = f2bf(v.z); o.w = f2bf(v.w);
        *(ushort4*)(p.Qb + (size_t)row * 512 + col) = o;
    }
}

// ---------------------------------------------------------------------------
// deformable sampling v5: block = 4 tokens, 4 waves; wave = one token.
// Phase 1: 512 (tl,h,s) slots on 256 threads (2 each); softmax via width-16
//   shuffles with denom folded into weights; clamped byte indices +
//   validity-zeroed weights -> LDS, sample dim padded 16->17 (conflict-free).
// Phase 2: 8 lanes per head, lane owns 8 packed bf16 channels (dwordx4
//   gathers, 16 B/lane), 16 samples x 4 unconditional corners.
// ---------------------------------------------------------------------------
__global__ __launch_bounds__(256) void sample_attn(
    const unsigned short* __restrict__ Vp, const unsigned short* __restrict__ OFFB,
    const unsigned short* __restrict__ ATT,
    const float* __restrict__ rf0, const float* __restrict__ rf1,
    const float* __restrict__ rf2, const float* __restrict__ rf3,
    unsigned short* __restrict__ ACCb)
{
    __shared__ int   midx[4][8][17][4];   // 8704 B
    __shared__ float mw[4][8][17][4];     // 8704 B
    const int tid = threadIdx.x;

    // ---- phase 1: 2 slots per thread; slot = (tl, h, s) ----
#pragma unroll
    for (int i = 0; i < 2; ++i) {
        const int slot = i * 256 + tid;
        const int tl = slot >> 7;          // 0..3
        const int h  = (slot >> 4) & 7;
        const int s  = slot & 15;
        const int t  = blockIdx.x * 4 + tl;
        const int li = s >> 2;

        int soff, area;
        const float* rp;
        if (t < 12544)      { soff = 0;     area = 3136; rp = rf0 + (size_t)t * 2; }
        else if (t < 15680) { soff = 12544; area = 784;  rp = rf1 + (size_t)(t - 12544) * 2; }
        else if (t < 16464) { soff = 15680; area = 196;  rp = rf2 + (size_t)(t - 15680) * 2; }
        else                { soff = 16464; area = 49;   rp = rf3 + (size_t)(t - 16464) * 2; }
        const int b = (t - soff) / area;

        // softmax over 16 logits of this head (width-16 shuffle groups)
        float logit = bf2f(ATT[(size_t)t * 128 + h * 16 + s]);
        float mx = logit;
#pragma unroll
        for (int o = 8; o > 0; o >>= 1) mx = fmaxf(mx, __shfl_xor(mx, o, 16));
        float e = __expf(logit - mx);
        float sumv = e;
#pragma unroll
        for (int o = 8; o > 0; o >>= 1) sumv += __shfl_xor(sumv, o, 16);
        const float ew = e / sumv;         // softmax denom folded in

        // coords: (rx + ox/wl)*wl - 0.5 == rx*wl + ox - 0.5
        const int wl = 56 >> li;
        const int lvlbase = (li == 0) ? 0 : (li == 1) ? 12544 : (li == 2) ? 15680 : 16464;
        const int base = lvlbase + b * wl * wl;
        const float rx = rp[0], ry = rp[1];
        const unsigned off2 = *(const unsigned*)(OFFB + (size_t)t * 256 + h * 32 + s * 2);
        const float ox = bflo(off2);
        const float oy = bfhi(off2);
        const float x = rx * (float)wl + ox - 0.5f;
        const float y = ry * (float)wl + oy - 0.5f;
        const float x0f = floorf(x), y0f = floorf(y);
        const float wx1 = x - x0f, wx0 = 1.f - wx1;
        const float wy1 = y - y0f, wy0 = 1.f - wy1;
        const int x0 = (int)x0f, y0 = (int)y0f;
        const int x1 = x0 + 1, y1 = y0 + 1;
        const int xc0 = min(max(x0, 0), wl - 1), xc1 = min(max(x1, 0), wl - 1);
        const int yc0 = min(max(y0, 0), wl - 1), yc1 = min(max(y1, 0), wl - 1);
        const float fx0 = (x0 >= 0 && x0 < wl) ? 1.f : 0.f;
        const float fx1 = (x1 >= 0 && x1 < wl) ? 1.f : 0.f;
        const float fy0 = (y0 >= 0 && y0 < wl) ? 1.f : 0.f;
        const float fy1 = (y1 >= 0 && y1 < wl) ? 1.f : 0.f;
        const int hb2 = h * 128;           // head base, BYTES (64 ch * 2B)
        int4 I;
        I.x = (base + yc0 * wl + xc0) * 1024 + hb2;   // *512 elem *2B
        I.y = (base + yc0 * wl + xc1) * 1024 + hb2;
        I.z = (base + yc1 * wl + xc0) * 1024 + hb2;
        I.w = (base + yc1 * wl + xc1) * 1024 + hb2;
        float4 Wt;
        Wt.x = wx0 * wy0 * fx0 * fy0 * ew;
        Wt.y = wx1 * wy0 * fx1 * fy0 * ew;
        Wt.z = wx0 * wy1 * fx0 * fy1 * ew;
        Wt.w = wx1 * wy1 * fx1 * fy1 * ew;
        *(int4*)&midx[tl][h][s][0] = I;
        *(float4*)&mw[tl][h][s][0] = Wt;
    }
    __syncthreads();

    // ---- phase 2: wave = token, 8 lanes/head, lane owns 8 channels ----
    const int wave = tid >> 6;
    const int lane = tid & 63;
    const int tl = wave;
    const int h  = lane >> 3;
    const int t  = blockIdx.x * 4 + tl;
    const int off16 = (lane & 7) * 16;     // byte offset within 128B head row
    const char* vb = (const char*)Vp;
    float a0 = 0.f, a1 = 0.f, a2 = 0.f, a3 = 0.f;
    float a4 = 0.f, a5 = 0.f, a6 = 0.f, a7 = 0.f;
#pragma unroll
    for (int s = 0; s < 16; ++s) {
        const int4   I = *(const int4*)&midx[tl][h][s][0];
        const float4 W = *(const float4*)&mw[tl][h][s][0];
        const uint4 u0 = *(const uint4*)(vb + (I.x + off16));
        const uint4 u1 = *(const uint4*)(vb + (I.y + off16));
        const uint4 u2 = *(const uint4*)(vb + (I.z + off16));
        const uint4 u3 = *(const uint4*)(vb + (I.w + off16));
        a0 += W.x * bflo(u0.x); a1 += W.x * bfhi(u0.x); a2 += W.x * bflo(u0.y); a3 += W.x * bfhi(u0.y);
        a4 += W.x * bflo(u0.z); a5 += W.x * bfhi(u0.z); a6 += W.x * bflo(u0.w); a7 += W.x * bfhi(u0.w);
        a0 += W.y * bflo(u1.x); a1 += W.y * bfhi(u1.x); a2 += W.y * bflo(u1.y); a3 += W.y * bfhi(u1.y);
        a4 += W.y * bflo(u1.z); a5 += W.y * bfhi(u1.z); a6 += W.y * bflo(u1.w); a7 += W.y * bfhi(u1.w);
        a0 += W.z * bflo(u2.x); a1 += W.z * bfhi(u2.x); a2 += W.z * bflo(u2.y); a3 += W.z * bfhi(u2.y);
        a4 += W.z * bflo(u2.z); a5 += W.z * bfhi(u2.z); a6 += W.z * bflo(u2.w); a7 += W.z * bfhi(u2.w);
        a0 += W.w * bflo(u3.x); a1 += W.w * bfhi(u3.x); a2 += W.w * bflo(u3.y); a3 += W.w * bfhi(u3.y);
        a4 += W.w * bflo(u3.z); a5 += W.w * bfhi(u3.z); a6 += W.w * bflo(u3.w); a7 += W.w * bfhi(u3.w);
    }
    uint4 o;
    o.x = ((unsigned)f2bf(a1) << 16) | f2bf(a0);
    o.y = ((unsigned)f2bf(a3) << 16) | f2bf(a2);
    o.z = ((unsigned)f2bf(a5) << 16) | f2bf(a4);
    o.w = ((unsigned)f2bf(a7) << 16) | f2bf(a6);
    *(uint4*)((char*)ACCb + (size_t)t * 1024 + h * 128 + off16) = o;
}

// in-place layernorm on bf16 rows of 512 (fp32 stats)
__global__ __launch_bounds__(256) void ln_bf16(
    unsigned short* __restrict__ X, const float* __restrict__ g, const float* __restrict__ be)
{
    const int row = blockIdx.x;
    unsigned short* xr = X + (size_t)row * 512;
    const int tid = threadIdx.x;
    float v0 = bf2f(xr[tid]);
    float v1 = bf2f(xr[tid + 256]);
    float s = v0 + v1;
    float ss = v0 * v0 + v1 * v1;
#pragma unroll
    for (int o = 32; o > 0; o >>= 1) {
        s += __shfl_down(s, o, 64);
        ss += __shfl_down(ss, o, 64);
    }
    __shared__ float sm[4], sm2[4];
    const int w = tid >> 6;
    if ((tid & 63) == 0) { sm[w] = s; sm2[w] = ss; }
    __syncthreads();
    if (tid == 0) {
        sm[0] = sm[0] + sm[1] + sm[2] + sm[3];
        sm2[0] = sm2[0] + sm2[1] + sm2[2] + sm2[3];
    }
    __syncthreads();
    const float mu = sm[0] * (1.f / 512.f);
    const float var = sm2[0] * (1.f / 512.f) - mu * mu;
    const float rs = rsqrtf(var + 1e-5f);
    xr[tid]       = f2bf((v0 - mu) * rs * g[tid]       + be[tid]);
    xr[tid + 256] = f2bf((v1 - mu) * rs * g[tid + 256] + be[tid + 256]);
}

// final fused kernel: per OUTPUT row r — sum the two split-K partials
// (P0 in ws, P1 already in d_out), add X1b residual (inverse-permuted),
// layernorm, write d_out in place. Each block owns row r exclusively.
__global__ __launch_bounds__(256) void ln_final(
    float* __restrict__ OutD, const float* __restrict__ P0,
    const unsigned short* __restrict__ X1b,
    const float* __restrict__ g, const float* __restrict__ be)
{
    const int r = blockIdx.x;
    const int t = inv_permute_row(r);
    float* xr = OutD + (size_t)r * 512;
    const float* p0 = P0 + (size_t)r * 512;
    const unsigned short* res = X1b + (size_t)t * 512;
    const int tid = threadIdx.x;
    float v0 = p0[tid]       + xr[tid]       + bf2f(res[tid]);
    float v1 = p0[tid + 256] + xr[tid + 256] + bf2f(res[tid + 256]);
    float s = v0 + v1;
    float ss = v0 * v0 + v1 * v1;
#pragma unroll
    for (int o = 32; o > 0; o >>= 1) {
        s += __shfl_down(s, o, 64);
        ss += __shfl_down(ss, o, 64);
    }
    __shared__ float sm[4], sm2[4];
    const int w = tid >> 6;
    if ((tid & 63) == 0) { sm[w] = s; sm2[w] = ss; }
    __syncthreads();
    if (tid == 0) {
        sm[0] = sm[0] + sm[1] + sm[2] + sm[3];
        sm2[0] = sm2[0] + sm2[1] + sm2[2] + sm2[3];
    }
    __syncthreads();
    const float mu = sm[0] * (1.f / 512.f);
    const float var = sm2[0] * (1.f / 512.f) - mu * mu;
    const float rs = rsqrtf(var + 1e-5f);
    xr[tid]       = (v0 - mu) * rs * g[tid]       + be[tid];
    xr[tid + 256] = (v1 - mu) * rs * g[tid + 256] + be[tid + 256];
}

extern "C" void kernel_launch(void* const* d_in, const int* in_sizes, int n_in,
                              void* d_out, int out_size, void* d_ws, size_t ws_size,
                              hipStream_t stream)
{
    const float* src[4] = { (const float*)d_in[0], (const float*)d_in[2],
                            (const float*)d_in[4], (const float*)d_in[6] };
    const float* ref[4] = { (const float*)d_in[1], (const float*)d_in[3],
                            (const float*)d_in[5], (const float*)d_in[7] };
    const float* Wv    = (const float*)d_in[8];
    const float* bv    = (const float*)d_in[9];
    const float* Woff  = (const float*)d_in[10];
    const float* boff  = (const float*)d_in[11];
    const float* Wattn = (const float*)d_in[12];
    const float* battn = (const float*)d_in[13];
    const float* Wo    = (const float*)d_in[14];
    const float* bo    = (const float*)d_in[15];
    const float* W1    = (const float*)d_in[16];
    const float* b1    = (const float*)d_in[17];
    const float* W2    = (const float*)d_in[18];
    const float* b2    = (const float*)d_in[19];
    const float* g1    = (const float*)d_in[20];
    const float* be1   = (const float*)d_in[21];
    const float* g2    = (const float*)d_in[22];
    const float* be2   = (const float*)d_in[23];

    // workspace layout (bf16 == unsigned short)
    unsigned short* w    = (unsigned short*)d_ws;
    unsigned short* Qb   = w;                              // [TPAD,512]
    unsigned short* Vp   = Qb   + (size_t)TPAD * 512;      // [TPAD,512]
    unsigned short* OFFB = Vp   + (size_t)TPAD * 512;      // [TPAD,256]
    unsigned short* ATT  = OFFB + (size_t)TPAD * 256;      // [TPAD,128]
    unsigned short* ACCb = ATT  + (size_t)TPAD * 128;      // [TPAD,512]
    unsigned short* X1b  = ACCb + (size_t)TPAD * 512;      // [TPAD,512]
    unsigned short* Fb   = X1b  + (size_t)TPAD * 512;      // [TPAD,2048]
    unsigned short* Wcat = Fb   + (size_t)TPAD * 2048;     // [896,512]
    unsigned short* Wot  = Wcat + (size_t)896 * 512;       // [512,512]
    unsigned short* W1t  = Wot  + (size_t)512 * 512;       // [2048,512]
    unsigned short* W2t  = W1t  + (size_t)2048 * 512;      // [512,2048]
    float* P0 = (float*)d_ws;   // a4 split-K partial kc0: [T,512] fp32,
                                // aliases Qb+Vp (both dead by a4)

    const dim3 blk(256);

    PrepArgs pp = {};
    pp.Wv = Wv; pp.Woff = Woff; pp.Wattn = Wattn; pp.Wo = Wo; pp.W1 = W1; pp.W2 = W2;
    pp.Wcat = Wcat; pp.Wot = Wot; pp.W1t = W1t; pp.W2t = W2t;
    pp.s0 = src[0]; pp.s1 = src[1]; pp.s2 = src[2]; pp.s3 = src[3];
    pp.Qb = Qb;
    prep<<<dim3(11082), blk, 0, stream>>>(pp);

    // fused V/off/attn projection: [T,512] @ [512,896]
    GemmArgs a1 = {};
    a1.A = Qb; a1.Bt = Wcat; a1.bias0 = bv; a1.bias1 = boff; a1.bias2 = battn;
    a1.out0 = Vp; a1.out1 = OFFB; a1.out2 = ATT;
    a1.M = TTOT; a1.N = 896; a1.Kd = 512; a1.lda = 512; a1.ldb = 512;
    gemm_mfma<EPI_SPLIT><<<dim3(7, 131), blk, 0, stream>>>(a1);

    sample_attn<<<dim3(TTOT / 4), blk, 0, stream>>>(Vp, OFFB, ATT,
                                                    ref[0], ref[1], ref[2], ref[3], ACCb);

    // output projection + residual(q from srcs)
    GemmArgs a2 = {};
    a2.A = ACCb; a2.Bt = Wot; a2.bias0 = bo;
    a2.s0 = src[0]; a2.s1 = src[1]; a2.s2 = src[2]; a2.s3 = src[3];
    a2.out0 = X1b; a2.M = TTOT; a2.N = 512; a2.Kd = 512; a2.lda = 512; a2.ldb = 512;
    gemm_mfma<EPI_RESID_SRC><<<dim3(4, 131), blk, 0, stream>>>(a2);

    ln_bf16<<<dim3(TTOT), blk, 0, stream>>>(X1b, g1, be1);

    // FFN up + relu
    GemmArgs a3 = {};
    a3.A = X1b; a3.Bt = W1t; a3.bias0 = b1;
    a3.out0 = Fb; a3.M = TTOT; a3.N = 2048; a3.Kd = 512; a3.lda = 512; a3.ldb = 512;
    gemm_mfma<EPI_RELU><<<dim3(16, 131), blk, 0, stream>>>(a3);

    // FFN down, split-K=2 in ONE launch (1048 blocks): kc0 -> P0 (+bias),
    // kc1 -> d_out; both fp32, scattered to permuted rows.
    GemmArgs a4 = {};
    a4.A = Fb; a4.Bt = W2t; a4.bias0 = b2;
    a4.out0 = P0; a4.out0b = d_out;
    a4.M = TTOT; a4.N = 512; a4.Kd = 1024; a4.lda = 2048; a4.ldb = 2048;
    gemm_mfma<EPI_PART><<<dim3(4, 131, 2), blk, 0, stream>>>(a4);

    // reduce partials + X1b residual + layernorm, in place on d_out
    ln_final<<<dim3(TTOT), blk, 0, stream>>>((float*)d_out, P0, X1b, g2, be2);
}